// Round 7
// baseline (492.108 us; speedup 1.0000x reference)
//
#include <hip/hip_runtime.h>
#include <hip/hip_bf16.h>
#include <cstdint>

typedef _Float16 half_t;
typedef _Float16 f16x8 __attribute__((ext_vector_type(8), aligned(16)));
typedef _Float16 f16x4 __attribute__((ext_vector_type(4), aligned(8)));
typedef _Float16 f16x2 __attribute__((ext_vector_type(2), aligned(4)));
typedef float f32x4 __attribute__((ext_vector_type(4)));

#define B_ 128
#define C_ 2048
#define N_ 196
#define S_ 312
#define L_ 300
#define LP 320   // padded L (10 x 32)
#define M_ 1024
#define NP 224   // padded N (14 x 16)
#define SP 384   // padded S for prep GEMMs (3 x 128)

// ---------------------------------------------------------------------------
// f32->f16 pad/convert: att [312,300]->[384,320], Wq [1024,300]->[1024,320],
// V_final [312,2048]->[384,2048].  grid (768,1,3), block 256
__global__ __launch_bounds__(256) void k_convert(const float* __restrict__ att, const float* __restrict__ Wq,
                                                 const float* __restrict__ V, half_t* __restrict__ atth,
                                                 half_t* __restrict__ wqh, half_t* __restrict__ vh) {
    int z = blockIdx.z;
    size_t e = ((size_t)blockIdx.x * 256 + threadIdx.x) * 4;
    if (z == 0) {
        if (e >= (size_t)SP * LP) return;
        int r = (int)(e / LP), c = (int)(e % LP);
        f16x4 h;
#pragma unroll
        for (int j = 0; j < 4; ++j) h[j] = (half_t)((r < S_ && c + j < L_) ? att[(size_t)r * L_ + c + j] : 0.f);
        *(f16x4*)&atth[e] = h;
    } else if (z == 1) {
        if (e >= (size_t)M_ * LP) return;
        int r = (int)(e / LP), c = (int)(e % LP);
        f16x4 h;
#pragma unroll
        for (int j = 0; j < 4; ++j) h[j] = (half_t)((c + j < L_) ? Wq[(size_t)r * L_ + c + j] : 0.f);
        *(f16x4*)&wqh[e] = h;
    } else {
        if (e >= (size_t)SP * C_) return;
        int r = (int)(e / C_);
        f16x4 h;
        if (r < S_) {
            float4 v = *(const float4*)&V[e];
            h[0] = (half_t)v.x; h[1] = (half_t)v.y; h[2] = (half_t)v.z; h[3] = (half_t)v.w;
        } else {
            h[0] = h[1] = h[2] = h[3] = (half_t)0.f;
        }
        *(f16x4*)&vh[e] = h;
    }
}

// ---------------------------------------------------------------------------
// Three transposes (f32 [R][Cc] -> f16 [Cc][R]) in one dispatch.
// z=0: Wk 1024x2048; z=1: Wo 2048x1024; z=2: Wv 1024x2048.  grid (32,32,3), block 256
__global__ __launch_bounds__(256) void k_transp3(const float* __restrict__ Wk, const float* __restrict__ Wo,
                                                 const float* __restrict__ Wv, half_t* __restrict__ WkT,
                                                 half_t* __restrict__ WoT, half_t* __restrict__ WvT) {
    __shared__ __attribute__((aligned(16))) half_t lsT[64][72];
    int z = blockIdx.z;
    const float* in; half_t* out; int R, Cc;
    if (z == 0)      { in = Wk; out = WkT; R = 1024; Cc = 2048; }
    else if (z == 1) { in = Wo; out = WoT; R = 2048; Cc = 1024; }
    else             { in = Wv; out = WvT; R = 1024; Cc = 2048; }
    if ((int)blockIdx.x >= Cc / 64 || (int)blockIdx.y >= R / 64) return;
    int c0 = blockIdx.x * 64, r0 = blockIdx.y * 64;
    int t = threadIdx.x;
#pragma unroll
    for (int i = 0; i < 4; ++i) {
        int Q = t + 256 * i;
        int rq = Q >> 5, cq = Q & 31;
        int rr = 2 * rq, cc = 2 * cq;
        const float* p0 = in + (size_t)(r0 + rr) * Cc + c0 + cc;
        float2 va = *(const float2*)p0;
        float2 vb = *(const float2*)(p0 + Cc);
        f16x2 w0; w0[0] = (half_t)va.x; w0[1] = (half_t)vb.x;
        f16x2 w1; w1[0] = (half_t)va.y; w1[1] = (half_t)vb.y;
        *(f16x2*)&lsT[cc][rr]     = w0;   // lsT[c][r] = in[r][c]
        *(f16x2*)&lsT[cc + 1][rr] = w1;
    }
    __syncthreads();
    int cl = t >> 2, ch = t & 3;
    f16x8 v0 = *(const f16x8*)&lsT[cl][ch * 16];
    f16x8 v1 = *(const f16x8*)&lsT[cl][ch * 16 + 8];
    half_t* po = out + (size_t)(c0 + cl) * R + r0 + ch * 16;
    *(f16x8*)po = v0;
    *(f16x8*)(po + 8) = v1;
}

// ---------------------------------------------------------------------------
// Dual-descriptor prep GEMM — direct-global-load, dual register bank, no LDS.
// C[r][col] = sum_k A[r][k] * Bm[col][k]; out row = r*rowmul + rowoff.
struct GDesc {
    const half_t* A; const half_t* Bm;
    float* outF; half_t* outH; const float* bias;
    int kdim; int ldo; int rowmul; int rowoff;
};

__global__ __launch_bounds__(256) void k_prep(GDesc d0, GDesc d1) {
    GDesc d = blockIdx.z ? d1 : d0;
    int t = threadIdx.x;
    int wid = t >> 6, lane = t & 63;
    const int rA0 = blockIdx.y * 128, rB0 = blockIdx.x * 128;
    int wr = wid >> 1, wc = wid & 1;
    int g = lane >> 4, l15 = lane & 15;
    const int kdim = d.kdim;
    const half_t* pa0 = d.A + ((size_t)rA0 + wr * 64 + l15) * kdim + g * 8;
    const half_t* pb0 = d.Bm + ((size_t)rB0 + wc * 64 + l15) * kdim + g * 8;
    f32x4 acc[4][4] = {};
    f16x8 aA[4], bA[4], aB[4], bB[4];
    int nk = kdim >> 5;   // always even here (10, 32, 64)

#define PLOADA(BK, off) _Pragma("unroll") for (int i = 0; i < 4; ++i) BK[i] = *(const f16x8*)(pa0 + (size_t)i * 16 * kdim + (off));
#define PLOADB(BK, off) _Pragma("unroll") for (int j = 0; j < 4; ++j) BK[j] = *(const f16x8*)(pb0 + (size_t)j * 16 * kdim + (off));
#define PMF(AB, BB)                                                                     \
    _Pragma("unroll") for (int i = 0; i < 4; ++i)                                       \
        _Pragma("unroll") for (int j = 0; j < 4; ++j)                                   \
            acc[i][j] = __builtin_amdgcn_mfma_f32_16x16x32_f16(AB[i], BB[j], acc[i][j], 0, 0, 0);

    PLOADA(aA, 0); PLOADB(bA, 0);
    for (int tk = 0; tk < nk; tk += 2) {
        PLOADA(aB, (tk + 1) * 32); PLOADB(bB, (tk + 1) * 32);
        PMF(aA, bA);
        if (tk + 2 < nk) { PLOADA(aA, (tk + 2) * 32); PLOADB(bA, (tk + 2) * 32); }
        PMF(aB, bB);
    }
#undef PLOADA
#undef PLOADB
#undef PMF

#pragma unroll
    for (int i = 0; i < 4; ++i) {
        int r0 = rA0 + wr * 64 + i * 16 + g * 4;
#pragma unroll
        for (int j = 0; j < 4; ++j) {
            int c0 = rB0 + wc * 64 + j * 16 + l15;
            float bval = d.bias ? d.bias[c0] : 0.f;
#pragma unroll
            for (int qq = 0; qq < 4; ++qq) {
                int rr = (r0 + qq) * d.rowmul + d.rowoff;
                float val = acc[i][j][qq];
                if (d.outF) d.outF[(size_t)rr * d.ldo + c0] = val;
                if (d.outH) d.outH[(size_t)rr * d.ldo + c0] = (half_t)(val + bval);
            }
        }
    }
}

// ---------------------------------------------------------------------------
// Fused main kernel — direct-global-load, dual register bank, NO LDS staging,
// no barriers in the K-loop.  Block (bb, st): scores & W2 for 64 s x one batch,
// softmax over n + dot in epilogue.  AstackP rows: 2s = Qk_s, 2s+1 = Wv2_s.
// Tile 128 rows x 224 cols, K=2048.  grid (nB, 5), block 256 (4 waves 2x2).
// Fragment pattern is 64B-coalesced: lanes (g,l15) cover 16 rows x 64B.
__global__ __launch_bounds__(256) void k_fused(const half_t* __restrict__ AstackP, const half_t* __restrict__ featT,
                                               const float* __restrict__ base, const float* __restrict__ ubv,
                                               float* __restrict__ out, int b0) {
    __shared__ float lsE[2][64][4];
    int t = threadIdx.x;
    int bb = blockIdx.x, st = blockIdx.y;
    int wid = t >> 6, lane = t & 63;
    int wr = wid >> 1, wc = wid & 1;
    int g = lane >> 4, l15 = lane & 15;
    const half_t* pa0 = AstackP + ((size_t)st * 128 + wr * 64 + l15) * C_ + g * 8;
    const half_t* pb0 = featT + ((size_t)bb * NP + wc * 112 + l15) * C_ + g * 8;
    f32x4 acc[4][7] = {};
    f16x8 aA[4], bA[7], aB[4], bB[7];

#define FLOADA(BK, off) _Pragma("unroll") for (int i = 0; i < 4; ++i) BK[i] = *(const f16x8*)(pa0 + (size_t)i * 16 * C_ + (off));
#define FLOADB(BK, off) _Pragma("unroll") for (int j = 0; j < 7; ++j) BK[j] = *(const f16x8*)(pb0 + (size_t)j * 16 * C_ + (off));
#define FMF(AB, BB)                                                                     \
    _Pragma("unroll") for (int i = 0; i < 4; ++i)                                       \
        _Pragma("unroll") for (int j = 0; j < 7; ++j)                                   \
            acc[i][j] = __builtin_amdgcn_mfma_f32_16x16x32_f16(AB[i], BB[j], acc[i][j], 0, 0, 0);

    FLOADA(aA, 0); FLOADB(bA, 0);
    for (int tk = 0; tk < 64; tk += 2) {
        FLOADA(aB, (tk + 1) * 32); FLOADB(bB, (tk + 1) * 32);
        FMF(aA, bA);
        if (tk + 2 < 64) { FLOADA(aA, (tk + 2) * 32); FLOADB(bA, (tk + 2) * 32); }
        FMF(aB, bB);
    }
#undef FLOADA
#undef FLOADB
#undef FMF

    // ---- epilogue: per s-row softmax over n + dot with W2 ----
    // lane's acc[i][j][qq]: row = wr*64+i*16+g*4+qq (even=score row 2s, odd=W2 row 2s+1),
    //                       col = wc*112+j*16+l15
#pragma unroll
    for (int i = 0; i < 4; ++i) {
#pragma unroll
        for (int pair = 0; pair < 2; ++pair) {
            float m = -3.0e38f;
#pragma unroll
            for (int j = 0; j < 7; ++j) {
                int col = wc * 112 + j * 16 + l15;
                if (col < N_) m = fmaxf(m, acc[i][j][2 * pair]);
            }
#pragma unroll
            for (int off = 1; off < 16; off <<= 1) m = fmaxf(m, __shfl_xor(m, off));
            float ls = 0.f, dt = 0.f;
#pragma unroll
            for (int j = 0; j < 7; ++j) {
                int col = wc * 112 + j * 16 + l15;
                if (col < N_) {
                    float p = __expf(acc[i][j][2 * pair] - m);
                    ls += p;
                    dt += p * acc[i][j][2 * pair + 1];
                }
            }
#pragma unroll
            for (int off = 1; off < 16; off <<= 1) { ls += __shfl_xor(ls, off); dt += __shfl_xor(dt, off); }
            if (l15 == 0) {
                int pr = wr * 32 + i * 8 + g * 2 + pair;
                lsE[wc][pr][0] = m; lsE[wc][pr][1] = ls; lsE[wc][pr][2] = dt;
            }
        }
    }
    __syncthreads();
    if (t < 64) {
        float m0 = lsE[0][t][0], l0 = lsE[0][t][1], dv0 = lsE[0][t][2];
        float m1 = lsE[1][t][0], l1 = lsE[1][t][1], dv1 = lsE[1][t][2];
        float M = fmaxf(m0, m1);
        float e0 = __expf(m0 - M), e1 = __expf(m1 - M);
        float L = l0 * e0 + l1 * e1, D = dv0 * e0 + dv1 * e1;
        int s = st * 64 + t;
        if (s < S_) {
            int bg = b0 + bb;
            out[(size_t)bg * S_ + s] = base[(size_t)bg * S_ + s] + ubv[s] + D / L;
        }
    }
}

// ---------------------------------------------------------------------------
// feat [nB][2048][196] f32 -> featT [(bb*224 + n)][2048] f16 (n zero-padded to 224)
// PLUS fused pool partials: poolp[(nT*B_ + bb)*C_ + c] = sum over this block's n of feat[b][c][n]
// grid (4 nT, 32 cT, nB), block 256
__global__ __launch_bounds__(256) void k_transf(const float* __restrict__ feat, half_t* __restrict__ featT,
                                                float* __restrict__ poolp) {
    __shared__ __attribute__((aligned(16))) half_t lsT[64][72];
    __shared__ float poolLs[64];
    int nT = blockIdx.x, cT = blockIdx.y, bb = blockIdx.z;
    int n0 = nT * 64, c0 = cT * 64;
    const float* fb = feat + (size_t)bb * C_ * N_;
    int t = threadIdx.x;
#pragma unroll
    for (int i = 0; i < 4; ++i) {
        int Q = t + 256 * i;
        int cq = Q >> 5, nq = Q & 31;
        int cc = 2 * cq, nn = 2 * nq;
        int n = n0 + nn;
        float2 va = {0, 0}, vb = {0, 0};
        if (n < N_) {
            const float* p0 = fb + (size_t)(c0 + cc) * N_ + n;
            va = *(const float2*)p0;
            vb = *(const float2*)(p0 + N_);
        }
        f16x2 w0; w0[0] = (half_t)va.x; w0[1] = (half_t)vb.x;
        f16x2 w1; w1[0] = (half_t)va.y; w1[1] = (half_t)vb.y;
        *(f16x2*)&lsT[nn][cc]     = w0;   // lsT[n][c]
        *(f16x2*)&lsT[nn + 1][cc] = w1;
        float sA = va.x + va.y, sB = vb.x + vb.y;
        for (int off = 16; off; off >>= 1) { sA += __shfl_xor(sA, off); sB += __shfl_xor(sB, off); }
        if ((t & 31) == 0) { poolLs[cc] = sA; poolLs[cc + 1] = sB; }
    }
    __syncthreads();
    int nl = t >> 2, ch = t & 3;
    int n = n0 + nl;
    if (n < NP) {   // rows [224,256) of nT=3 must NOT spill into the next batch's tile
        f16x8 v0 = *(const f16x8*)&lsT[nl][ch * 16];
        f16x8 v1 = *(const f16x8*)&lsT[nl][ch * 16 + 8];
        half_t* po = featT + ((size_t)bb * NP + n) * C_ + c0 + ch * 16;
        *(f16x8*)po = v0;
        *(f16x8*)(po + 8) = v1;
    }
    if (t < 64) poolp[((size_t)nT * B_ + bb) * C_ + c0 + t] = poolLs[t];
}

// ---------------------------------------------------------------------------
// base[b][s] = sum_c (mean_pool[b][c] + bo[c]) * V[s][c].  grid (4 sc, nB b), block 256
__global__ __launch_bounds__(256) void k_poolv(const float* __restrict__ poolp, const float* __restrict__ bo,
                                               const float* __restrict__ V, float* __restrict__ base) {
    int sc = blockIdx.x, b = blockIdx.y;
    __shared__ float w[C_];
    int t = threadIdx.x;
    for (int i = t; i < C_; i += 256) {
        float s = poolp[(size_t)b * C_ + i] + poolp[((size_t)B_ + b) * C_ + i] +
                  poolp[((size_t)2 * B_ + b) * C_ + i] + poolp[((size_t)3 * B_ + b) * C_ + i];
        w[i] = s * (1.0f / 196.0f) + bo[i];
    }
    __syncthreads();
    int wid = t >> 6, lane = t & 63;
    for (int s = sc * 78 + wid; s < sc * 78 + 78; s += 4) {
        const float* vr = V + (size_t)s * C_;
        float acc = 0;
#pragma unroll
        for (int i = 0; i < 32; ++i) acc += w[lane + 64 * i] * vr[lane + 64 * i];
        for (int off = 32; off; off >>= 1) acc += __shfl_xor(acc, off);
        if (lane == 0) base[(size_t)b * S_ + s] = acc;
    }
}

// ---------------------------------------------------------------------------
// ubv[s] = sum_m U[s][m]*bv[m].  grid 78, block 256 (wave per s)
__global__ __launch_bounds__(256) void k_ubv(const float* __restrict__ U, const float* __restrict__ bv,
                                             float* __restrict__ ubv) {
    int s = blockIdx.x * 4 + (threadIdx.x >> 6);
    int lane = threadIdx.x & 63;
    if (s >= S_) return;
    const float* ur = U + (size_t)s * M_;
    float acc = 0;
#pragma unroll
    for (int i = 0; i < 16; ++i) acc += ur[lane + 64 * i] * bv[lane + 64 * i];
    for (int off = 32; off; off >>= 1) acc += __shfl_xor(acc, off);
    if (lane == 0) ubv[s] = acc;
}

// ---------------------------------------------------------------------------
extern "C" void kernel_launch(void* const* d_in, const int* in_sizes, int n_in,
                              void* d_out, int out_size, void* d_ws, size_t ws_size,
                              hipStream_t stream) {
    const float* feat = (const float*)d_in[0];
    const float* att  = (const float*)d_in[1];
    const float* Wq   = (const float*)d_in[2];
    const float* bq   = (const float*)d_in[3];
    const float* Wk   = (const float*)d_in[4];
    /* bk = d_in[5] — per-s constant over n in scores: softmax-invariant, dropped */
    const float* Wv   = (const float*)d_in[6];
    const float* bv   = (const float*)d_in[7];
    const float* Wo   = (const float*)d_in[8];
    const float* bo   = (const float*)d_in[9];
    const float* V    = (const float*)d_in[10];
    float* out = (float*)d_out;

    auto AL = [](size_t x) { return (x + 255) & ~(size_t)255; };
    const size_t szAstk = (size_t)768 * C_ * 2;       // pair-interleaved [2s | 2s+1]
    const size_t szQh   = (size_t)SP * M_ * 2;
    const size_t szVh   = (size_t)SP * C_ * 2;
    const size_t szUf   = (size_t)SP * M_ * 4;
    const size_t szUh   = (size_t)SP * M_ * 2;
    const size_t szWT   = (size_t)C_ * M_ * 2;
    const size_t szAtth = (size_t)SP * LP * 2;
    const size_t szWqh  = (size_t)M_ * LP * 2;
    const size_t szPoolp = (size_t)4 * B_ * C_ * 4;
    const size_t szBase = (size_t)B_ * S_ * 4;
    const size_t szUbv  = (size_t)S_ * 4;
    size_t fixed = AL(szAstk) + AL(szQh) + AL(szVh) + AL(szUf) + AL(szUh) + 3 * AL(szWT) +
                   AL(szAtth) + AL(szWqh) + AL(szPoolp) + AL(szBase) + AL(szUbv);

    int nsplit = 1;
    while (nsplit < 32) {
        size_t nB = B_ / nsplit;
        size_t need = fixed + AL(nB * NP * C_ * 2 + 131072);
        if (need <= ws_size) break;
        nsplit *= 2;
    }
    int nB = B_ / nsplit;

    char* p = (char*)d_ws;
    half_t* AstackP = (half_t*)p; p += AL(szAstk);
    half_t* qh     = (half_t*)p; p += AL(szQh);
    half_t* Vh     = (half_t*)p; p += AL(szVh);
    float*  Uf     = (float*)p;  p += AL(szUf);
    half_t* Uh     = (half_t*)p; p += AL(szUh);
    half_t* WkT    = (half_t*)p; p += AL(szWT);
    half_t* WoT    = (half_t*)p; p += AL(szWT);
    half_t* WvT    = (half_t*)p; p += AL(szWT);
    half_t* atth   = (half_t*)p; p += AL(szAtth);
    half_t* wqh    = (half_t*)p; p += AL(szWqh);
    float*  poolp  = (float*)p;  p += AL(szPoolp);
    float*  base   = (float*)p;  p += AL(szBase);
    float*  ubv    = (float*)p;  p += AL(szUbv);
    half_t* featT  = (half_t*)p;

    // ---- batch-independent precompute ----
    k_convert<<<dim3(768, 1, 3), 256, 0, stream>>>(att, Wq, V, atth, wqh, Vh);
    k_transp3<<<dim3(32, 32, 3), 256, 0, stream>>>(Wk, Wo, Wv, WkT, WoT, WvT);
    // prepA: z0 q = att@Wq.T + bq (f16);  z1 U = V@Wo (f32 + f16)
    {
        GDesc dq{atth, wqh, nullptr, qh, bq, LP, M_, 1, 0};
        GDesc dU{Vh, WoT, Uf, Uh, nullptr, C_, M_, 1, 0};
        k_prep<<<dim3(8, 3, 2), 256, 0, stream>>>(dq, dU);
    }
    k_ubv<<<dim3(78), 256, 0, stream>>>(Uf, bv, ubv);
    // prepB: z0 Qk = q@Wk -> rows 2s;  z1 Wv2 = U@Wv -> rows 2s+1
    {
        GDesc dk{qh, WkT, nullptr, AstackP, nullptr, M_, C_, 2, 0};
        GDesc dv{Uh, WvT, nullptr, AstackP, nullptr, M_, C_, 2, 1};
        k_prep<<<dim3(16, 3, 2), 256, 0, stream>>>(dk, dv);
    }

    // ---- main per-batch-split pipeline ----
    for (int h = 0; h < nsplit; ++h) {
        const float* fh = feat + (size_t)h * nB * C_ * N_;
        k_transf<<<dim3(4, 32, nB), 256, 0, stream>>>(fh, featT, poolp);
        k_poolv<<<dim3(4, nB), 256, 0, stream>>>(poolp, bo, V, base + (size_t)h * nB * S_);
        k_fused<<<dim3(nB, 5), 256, 0, stream>>>(AstackP, featT, base, ubv, out, h * nB);
    }
}

// Round 8
// 270.021 us; speedup vs baseline: 1.8225x; 1.8225x over previous
//
#include <hip/hip_runtime.h>
#include <hip/hip_bf16.h>
#include <cstdint>

typedef _Float16 half_t;
typedef _Float16 f16x8 __attribute__((ext_vector_type(8), aligned(16)));
typedef _Float16 f16x4 __attribute__((ext_vector_type(4), aligned(8)));
typedef _Float16 f16x2 __attribute__((ext_vector_type(2), aligned(4)));
typedef float f32x4 __attribute__((ext_vector_type(4)));

#define B_ 128
#define C_ 2048
#define N_ 196
#define S_ 312
#define L_ 300
#define LP 320   // padded L (10 x 32)
#define M_ 1024
#define NP 224   // padded N (14 x 16)
#define SP 384   // padded S for prep GEMMs (3 x 128)

// ---- async global->LDS, 16B per lane ----
__device__ __forceinline__ void gload16(const half_t* g, half_t* l) {
    __builtin_amdgcn_global_load_lds((const __attribute__((address_space(1))) void*)g,
                                     (__attribute__((address_space(3))) void*)l, 16, 0, 0);
}

// ---------------------------------------------------------------------------
// f32->f16 pad/convert: att [312,300]->[384,320], Wq [1024,300]->[1024,320],
// V_final [312,2048]->[384,2048].  grid (768,1,3), block 256
__global__ __launch_bounds__(256) void k_convert(const float* __restrict__ att, const float* __restrict__ Wq,
                                                 const float* __restrict__ V, half_t* __restrict__ atth,
                                                 half_t* __restrict__ wqh, half_t* __restrict__ vh) {
    int z = blockIdx.z;
    size_t e = ((size_t)blockIdx.x * 256 + threadIdx.x) * 4;
    if (z == 0) {
        if (e >= (size_t)SP * LP) return;
        int r = (int)(e / LP), c = (int)(e % LP);
        f16x4 h;
#pragma unroll
        for (int j = 0; j < 4; ++j) h[j] = (half_t)((r < S_ && c + j < L_) ? att[(size_t)r * L_ + c + j] : 0.f);
        *(f16x4*)&atth[e] = h;
    } else if (z == 1) {
        if (e >= (size_t)M_ * LP) return;
        int r = (int)(e / LP), c = (int)(e % LP);
        f16x4 h;
#pragma unroll
        for (int j = 0; j < 4; ++j) h[j] = (half_t)((c + j < L_) ? Wq[(size_t)r * L_ + c + j] : 0.f);
        *(f16x4*)&wqh[e] = h;
    } else {
        if (e >= (size_t)SP * C_) return;
        int r = (int)(e / C_);
        f16x4 h;
        if (r < S_) {
            float4 v = *(const float4*)&V[e];
            h[0] = (half_t)v.x; h[1] = (half_t)v.y; h[2] = (half_t)v.z; h[3] = (half_t)v.w;
        } else {
            h[0] = h[1] = h[2] = h[3] = (half_t)0.f;
        }
        *(f16x4*)&vh[e] = h;
    }
}

// ---------------------------------------------------------------------------
// Three transposes (f32 [R][Cc] -> f16 [Cc][R]) in one dispatch.
// z=0: Wk 1024x2048; z=1: Wo 2048x1024; z=2: Wv 1024x2048.  grid (32,32,3), block 256
__global__ __launch_bounds__(256) void k_transp3(const float* __restrict__ Wk, const float* __restrict__ Wo,
                                                 const float* __restrict__ Wv, half_t* __restrict__ WkT,
                                                 half_t* __restrict__ WoT, half_t* __restrict__ WvT) {
    __shared__ __attribute__((aligned(16))) half_t lsT[64][72];
    int z = blockIdx.z;
    const float* in; half_t* out; int R, Cc;
    if (z == 0)      { in = Wk; out = WkT; R = 1024; Cc = 2048; }
    else if (z == 1) { in = Wo; out = WoT; R = 2048; Cc = 1024; }
    else             { in = Wv; out = WvT; R = 1024; Cc = 2048; }
    if ((int)blockIdx.x >= Cc / 64 || (int)blockIdx.y >= R / 64) return;
    int c0 = blockIdx.x * 64, r0 = blockIdx.y * 64;
    int t = threadIdx.x;
#pragma unroll
    for (int i = 0; i < 4; ++i) {
        int Q = t + 256 * i;
        int rq = Q >> 5, cq = Q & 31;
        int rr = 2 * rq, cc = 2 * cq;
        const float* p0 = in + (size_t)(r0 + rr) * Cc + c0 + cc;
        float2 va = *(const float2*)p0;
        float2 vb = *(const float2*)(p0 + Cc);
        f16x2 w0; w0[0] = (half_t)va.x; w0[1] = (half_t)vb.x;
        f16x2 w1; w1[0] = (half_t)va.y; w1[1] = (half_t)vb.y;
        *(f16x2*)&lsT[cc][rr]     = w0;   // lsT[c][r] = in[r][c]
        *(f16x2*)&lsT[cc + 1][rr] = w1;
    }
    __syncthreads();
    int cl = t >> 2, ch = t & 3;
    f16x8 v0 = *(const f16x8*)&lsT[cl][ch * 16];
    f16x8 v1 = *(const f16x8*)&lsT[cl][ch * 16 + 8];
    half_t* po = out + (size_t)(c0 + cl) * R + r0 + ch * 16;
    *(f16x8*)po = v0;
    *(f16x8*)(po + 8) = v1;
}

// ---------------------------------------------------------------------------
// Dual-descriptor prep GEMM (counted-vmcnt 3-slot ring + XOR-swizzled LDS) — R5-proven.
// C[r][col] = sum_k A[r][k] * Bm[col][k]; out row = r*rowmul + rowoff.
struct GDesc {
    const half_t* A; const half_t* Bm;
    float* outF; half_t* outH; const float* bias;
    int kdim; int ldo; int rowmul; int rowoff;
};

__global__ __launch_bounds__(256) void k_prep(GDesc d0, GDesc d1) {
    GDesc d = blockIdx.z ? d1 : d0;
    __shared__ __attribute__((aligned(16))) half_t lsA[3][128 * 32];
    __shared__ __attribute__((aligned(16))) half_t lsB[3][128 * 32];
    int t = threadIdx.x;
    int wid = t >> 6, lane = t & 63;
    const int rA0 = blockIdx.y * 128, rB0 = blockIdx.x * 128;
    int wr = wid >> 1, wc = wid & 1;
    int g = lane >> 4, l15 = lane & 15;
    const int r_ = t >> 2;
    const int gsrc = ((t & 3) ^ ((t >> 3) & 3)) * 8;  // pre-swizzled source chunk
    const int kdim = d.kdim;
    const half_t* pA  = d.A + (size_t)(rA0 + r_) * kdim + gsrc;
    const half_t* pA2 = pA + (size_t)64 * kdim;
    const half_t* pB  = d.Bm + (size_t)(rB0 + r_) * kdim + gsrc;
    const half_t* pB2 = pB + (size_t)64 * kdim;
    const int lo = t * 8;
    const int xsw = ((l15 >> 1) & 3) * 8;
    f32x4 acc[4][4] = {};
    int nk = kdim >> 5;

#define STAGE(slot, kc)                              \
    do {                                             \
        gload16(pA + (kc), &lsA[slot][lo]);          \
        gload16(pA2 + (kc), &lsA[slot][lo + 2048]);  \
        gload16(pB + (kc), &lsB[slot][lo]);          \
        gload16(pB2 + (kc), &lsB[slot][lo + 2048]);  \
    } while (0)

    STAGE(0, 0);
    STAGE(1, 32);
    int cur = 0, nxt = 2;
    for (int tk = 0; tk < nk; ++tk) {
        if (tk == nk - 1) asm volatile("s_waitcnt vmcnt(0)" ::: "memory");
        else              asm volatile("s_waitcnt vmcnt(4)" ::: "memory");
        __builtin_amdgcn_s_barrier();
        __builtin_amdgcn_sched_barrier(0);
        f16x8 af[4], bf[4];
#pragma unroll
        for (int i = 0; i < 4; ++i) af[i] = *(const f16x8*)&lsA[cur][(wr * 64 + i * 16 + l15) * 32 + ((g * 8) ^ xsw)];
#pragma unroll
        for (int j = 0; j < 4; ++j) bf[j] = *(const f16x8*)&lsB[cur][(wc * 64 + j * 16 + l15) * 32 + ((g * 8) ^ xsw)];
        if (tk + 2 < nk) STAGE(nxt, (tk + 2) * 32);
#pragma unroll
        for (int i = 0; i < 4; ++i)
#pragma unroll
            for (int j = 0; j < 4; ++j)
                acc[i][j] = __builtin_amdgcn_mfma_f32_16x16x32_f16(af[i], bf[j], acc[i][j], 0, 0, 0);
        cur = (cur == 2) ? 0 : cur + 1;
        nxt = (nxt == 2) ? 0 : nxt + 1;
    }
#undef STAGE

#pragma unroll
    for (int i = 0; i < 4; ++i) {
        int r0 = rA0 + wr * 64 + i * 16 + g * 4;
#pragma unroll
        for (int j = 0; j < 4; ++j) {
            int c0 = rB0 + wc * 64 + j * 16 + l15;
            float bval = d.bias ? d.bias[c0] : 0.f;
#pragma unroll
            for (int qq = 0; qq < 4; ++qq) {
                int rr = (r0 + qq) * d.rowmul + d.rowoff;
                float val = acc[i][j][qq];
                if (d.outF) d.outF[(size_t)rr * d.ldo + c0] = val;
                if (d.outH) d.outH[(size_t)rr * d.ldo + c0] = (half_t)(val + bval);
            }
        }
    }
}

// ---------------------------------------------------------------------------
// Fused main kernel — 160-row tile, grid 512 = exactly 2 blocks/CU (no tail),
// 2-slot LDS ring with counted sync: vmcnt(0); barrier; STAGE(next); ds_read(cur);
// lgkm(0); MFMA.  Reads of a slot are lgkm-drained before the barrier that
// precedes its overwrite.  Staging is vmcnt-uniform: 7 gload16/thread
// (A over-staged to 192 rows, B to 256 rows).
// AstackP rows interleaved: 2s = Qk_s, 2s+1 = Wv2_s.  Block (bb, st): s in
// [st*80, st*80+80), all 224 cols.  4 waves 2x2; wave = 80 rows x 112 cols.
__global__ __launch_bounds__(256) void k_fused(const half_t* __restrict__ AstackP, const half_t* __restrict__ featT,
                                               const float* __restrict__ base2, float* __restrict__ out, int b0) {
    __shared__ __attribute__((aligned(16))) half_t lsA[2][192 * 32];
    __shared__ __attribute__((aligned(16))) half_t lsB[2][256 * 32];
    __shared__ float lsE[2][80][4];
    int t = threadIdx.x;
    int bb = blockIdx.x, st = blockIdx.y;
    int wid = t >> 6, lane = t & 63;
    int wr = wid >> 1, wc = wid & 1;
    int g = lane >> 4, l15 = lane & 15;
    const int gsrc = ((t & 3) ^ ((t >> 3) & 3)) * 8;
    // A: stage 192 rows (rows >=160 unused; AstackP has 768 rows so in-bounds for st=3)
    const half_t* pA  = AstackP + ((size_t)st * 160 + (t >> 2)) * C_ + gsrc;
    const half_t* pA2 = pA + (size_t)64 * C_;
    const half_t* pA3 = pA + (size_t)128 * C_;
    // B: stage 256 rows (32 over-stage; ws has +128KB slack for bb=127)
    const half_t* pB  = featT + ((size_t)bb * NP + (t >> 2)) * C_ + gsrc;
    const half_t* pB2 = pB + (size_t)64 * C_;
    const half_t* pB3 = pB + (size_t)128 * C_;
    const half_t* pB4 = pB + (size_t)192 * C_;
    const int lo = t * 8;
    const int xsw = ((l15 >> 1) & 3) * 8;
    f32x4 acc[5][7] = {};

#define FSTAGE(slot, kc)                             \
    do {                                             \
        gload16(pA + (kc), &lsA[slot][lo]);          \
        gload16(pA2 + (kc), &lsA[slot][lo + 2048]);  \
        gload16(pA3 + (kc), &lsA[slot][lo + 4096]);  \
        gload16(pB + (kc), &lsB[slot][lo]);          \
        gload16(pB2 + (kc), &lsB[slot][lo + 2048]);  \
        gload16(pB3 + (kc), &lsB[slot][lo + 4096]);  \
        gload16(pB4 + (kc), &lsB[slot][lo + 6144]);  \
    } while (0)

    FSTAGE(0, 0);
    for (int tk = 0; tk < 64; ++tk) {
        int cur = tk & 1;
        asm volatile("s_waitcnt vmcnt(0)" ::: "memory");   // stage tk landed (only one in flight)
        __builtin_amdgcn_s_barrier();                      // all waves' stage tk landed; all reads of slot cur^1 drained
        __builtin_amdgcn_sched_barrier(0);
        if (tk + 1 < 64) FSTAGE(cur ^ 1, (tk + 1) * 32);   // overwrite the slot everyone finished reading
        f16x8 af[5], bf[7];
#pragma unroll
        for (int i = 0; i < 5; ++i) af[i] = *(const f16x8*)&lsA[cur][(wr * 80 + i * 16 + l15) * 32 + ((g * 8) ^ xsw)];
#pragma unroll
        for (int j = 0; j < 7; ++j) bf[j] = *(const f16x8*)&lsB[cur][(wc * 112 + j * 16 + l15) * 32 + ((g * 8) ^ xsw)];
        asm volatile("s_waitcnt lgkmcnt(0)" ::: "memory"); // my reads done (before MFMA and before next barrier)
        __builtin_amdgcn_sched_barrier(0);
#pragma unroll
        for (int i = 0; i < 5; ++i)
#pragma unroll
            for (int j = 0; j < 7; ++j)
                acc[i][j] = __builtin_amdgcn_mfma_f32_16x16x32_f16(af[i], bf[j], acc[i][j], 0, 0, 0);
    }
#undef FSTAGE

    // ---- epilogue: per s-row softmax over n + dot with W2 ----
    // lane's acc[i][j][qq]: row = wr*80+i*16+g*4+qq (even=score 2s, odd=W2 2s+1),
    //                       col = wc*112+j*16+l15.  qq=0,1 -> pair 0; qq=2,3 -> pair 1.
#pragma unroll
    for (int i = 0; i < 5; ++i) {
#pragma unroll
        for (int pair = 0; pair < 2; ++pair) {
            float m = -3.0e38f;
#pragma unroll
            for (int j = 0; j < 7; ++j) {
                int col = wc * 112 + j * 16 + l15;
                if (col < N_) m = fmaxf(m, acc[i][j][2 * pair]);
            }
#pragma unroll
            for (int off = 1; off < 16; off <<= 1) m = fmaxf(m, __shfl_xor(m, off));
            float ls = 0.f, dt = 0.f;
#pragma unroll
            for (int j = 0; j < 7; ++j) {
                int col = wc * 112 + j * 16 + l15;
                if (col < N_) {
                    float p = __expf(acc[i][j][2 * pair] - m);
                    ls += p;
                    dt += p * acc[i][j][2 * pair + 1];
                }
            }
#pragma unroll
            for (int off = 1; off < 16; off <<= 1) { ls += __shfl_xor(ls, off); dt += __shfl_xor(dt, off); }
            if (l15 == 0) {
                int pr = wr * 40 + i * 8 + g * 2 + pair;
                lsE[wc][pr][0] = m; lsE[wc][pr][1] = ls; lsE[wc][pr][2] = dt;
            }
        }
    }
    __syncthreads();
    if (t < 80) {
        float m0 = lsE[0][t][0], l0 = lsE[0][t][1], dv0 = lsE[0][t][2];
        float m1 = lsE[1][t][0], l1 = lsE[1][t][1], dv1 = lsE[1][t][2];
        float M = fmaxf(m0, m1);
        float e0 = __expf(m0 - M), e1 = __expf(m1 - M);
        float L = l0 * e0 + l1 * e1, D = dv0 * e0 + dv1 * e1;
        int s = st * 80 + t;
        if (s < S_) {
            int bg = b0 + bb;
            out[(size_t)bg * S_ + s] = base2[(size_t)bg * S_ + s] + D / L;
        }
    }
}

// ---------------------------------------------------------------------------
// feat [nB][2048][196] f32 -> featT [(bb*224 + n)][2048] f16 (n zero-padded to 224)
// PLUS fused pool partials.  grid (4 nT, 32 cT, nB), block 256
__global__ __launch_bounds__(256) void k_transf(const float* __restrict__ feat, half_t* __restrict__ featT,
                                                float* __restrict__ poolp) {
    __shared__ __attribute__((aligned(16))) half_t lsT[64][72];
    __shared__ float poolLs[64];
    int nT = blockIdx.x, cT = blockIdx.y, bb = blockIdx.z;
    int n0 = nT * 64, c0 = cT * 64;
    const float* fb = feat + (size_t)bb * C_ * N_;
    int t = threadIdx.x;
#pragma unroll
    for (int i = 0; i < 4; ++i) {
        int Q = t + 256 * i;
        int cq = Q >> 5, nq = Q & 31;
        int cc = 2 * cq, nn = 2 * nq;
        int n = n0 + nn;
        float2 va = {0, 0}, vb = {0, 0};
        if (n < N_) {
            const float* p0 = fb + (size_t)(c0 + cc) * N_ + n;
            va = *(const float2*)p0;
            vb = *(const float2*)(p0 + N_);
        }
        f16x2 w0; w0[0] = (half_t)va.x; w0[1] = (half_t)vb.x;
        f16x2 w1; w1[0] = (half_t)va.y; w1[1] = (half_t)vb.y;
        *(f16x2*)&lsT[nn][cc]     = w0;   // lsT[n][c]
        *(f16x2*)&lsT[nn + 1][cc] = w1;
        float sA = va.x + va.y, sB = vb.x + vb.y;
        for (int off = 16; off; off >>= 1) { sA += __shfl_xor(sA, off); sB += __shfl_xor(sB, off); }
        if ((t & 31) == 0) { poolLs[cc] = sA; poolLs[cc + 1] = sB; }
    }
    __syncthreads();
    int nl = t >> 2, ch = t & 3;
    int n = n0 + nl;
    if (n < NP) {
        f16x8 v0 = *(const f16x8*)&lsT[nl][ch * 16];
        f16x8 v1 = *(const f16x8*)&lsT[nl][ch * 16 + 8];
        half_t* po = featT + ((size_t)bb * NP + n) * C_ + c0 + ch * 16;
        *(f16x8*)po = v0;
        *(f16x8*)(po + 8) = v1;
    }
    if (t < 64) poolp[((size_t)nT * B_ + bb) * C_ + c0 + t] = poolLs[t];
}

// ---------------------------------------------------------------------------
// Wobv[c] = sum_m Wo[c][m] * bv[m].  grid 512, block 256 (wave per c-row)
__global__ __launch_bounds__(256) void k_wobv(const float* __restrict__ Wo, const float* __restrict__ bv,
                                              float* __restrict__ Wobv) {
    int c = blockIdx.x * 4 + (threadIdx.x >> 6);
    int lane = threadIdx.x & 63;
    const float* wr_ = Wo + (size_t)c * M_;
    float acc = 0;
#pragma unroll
    for (int i = 0; i < 16; ++i) acc += wr_[lane + 64 * i] * bv[lane + 64 * i];
    for (int off = 32; off; off >>= 1) acc += __shfl_xor(acc, off);
    if (lane == 0) Wobv[c] = acc;
}

// ---------------------------------------------------------------------------
// base2[b][s] = sum_c (mean_pool[b][c] + bo[c] + Wobv[c]) * V[s][c]  (ubv folded in).
// grid (4 sc, nB b), block 256
__global__ __launch_bounds__(256) void k_poolv(const float* __restrict__ poolp, const float* __restrict__ bo,
                                               const float* __restrict__ Wobv, const float* __restrict__ V,
                                               float* __restrict__ base2) {
    int sc = blockIdx.x, b = blockIdx.y;
    __shared__ float w[C_];
    int t = threadIdx.x;
    for (int i = t; i < C_; i += 256) {
        float s = poolp[(size_t)b * C_ + i] + poolp[((size_t)B_ + b) * C_ + i] +
                  poolp[((size_t)2 * B_ + b) * C_ + i] + poolp[((size_t)3 * B_ + b) * C_ + i];
        w[i] = s * (1.0f / 196.0f) + bo[i] + Wobv[i];
    }
    __syncthreads();
    int wid = t >> 6, lane = t & 63;
    for (int s = sc * 78 + wid; s < sc * 78 + 78; s += 4) {
        const float* vr = V + (size_t)s * C_;
        float acc = 0;
#pragma unroll
        for (int i = 0; i < 32; ++i) acc += w[lane + 64 * i] * vr[lane + 64 * i];
        for (int off = 32; off; off >>= 1) acc += __shfl_xor(acc, off);
        if (lane == 0) base2[(size_t)b * S_ + s] = acc;
    }
}

// ---------------------------------------------------------------------------
extern "C" void kernel_launch(void* const* d_in, const int* in_sizes, int n_in,
                              void* d_out, int out_size, void* d_ws, size_t ws_size,
                              hipStream_t stream) {
    const float* feat = (const float*)d_in[0];
    const float* att  = (const float*)d_in[1];
    const float* Wq   = (const float*)d_in[2];
    const float* bq   = (const float*)d_in[3];
    const float* Wk   = (const float*)d_in[4];
    /* bk = d_in[5] — per-s constant over n in scores: softmax-invariant, dropped */
    const float* Wv   = (const float*)d_in[6];
    const float* bv   = (const float*)d_in[7];
    const float* Wo   = (const float*)d_in[8];
    const float* bo   = (const float*)d_in[9];
    const float* V    = (const float*)d_in[10];
    float* out = (float*)d_out;

    auto AL = [](size_t x) { return (x + 255) & ~(size_t)255; };
    const size_t szAstk = (size_t)768 * C_ * 2;       // pair-interleaved [2s | 2s+1]
    const size_t szQh   = (size_t)SP * M_ * 2;
    const size_t szVh   = (size_t)SP * C_ * 2;
    const size_t szUh   = (size_t)SP * M_ * 2;
    const size_t szWT   = (size_t)C_ * M_ * 2;
    const size_t szAtth = (size_t)SP * LP * 2;
    const size_t szWqh  = (size_t)M_ * LP * 2;
    const size_t szPoolp = (size_t)4 * B_ * C_ * 4;
    const size_t szBase = (size_t)B_ * S_ * 4;
    const size_t szWobv = (size_t)C_ * 4;
    size_t fixed = AL(szAstk) + AL(szQh) + AL(szVh) + AL(szUh) + 3 * AL(szWT) +
                   AL(szAtth) + AL(szWqh) + AL(szPoolp) + AL(szBase) + AL(szWobv);

    int nsplit = 1;
    while (nsplit < 32) {
        size_t nB = B_ / nsplit;
        size_t need = fixed + AL(nB * NP * C_ * 2 + 131072);  // +128KB over-stage slack
        if (need <= ws_size) break;
        nsplit *= 2;
    }
    int nB = B_ / nsplit;

    char* p = (char*)d_ws;
    half_t* AstackP = (half_t*)p; p += AL(szAstk);
    half_t* qh     = (half_t*)p; p += AL(szQh);
    half_t* Vh     = (half_t*)p; p += AL(szVh);
    half_t* Uh     = (half_t*)p; p += AL(szUh);
    half_t* WkT    = (half_t*)p; p += AL(szWT);
    half_t* WoT    = (half_t*)p; p += AL(szWT);
    half_t* WvT    = (half_t*)p; p += AL(szWT);
    half_t* atth   = (half_t*)p; p += AL(szAtth);
    half_t* wqh    = (half_t*)p; p += AL(szWqh);
    float*  poolp  = (float*)p;  p += AL(szPoolp);
    float*  base2  = (float*)p;  p += AL(szBase);
    float*  Wobv   = (float*)p;  p += AL(szWobv);
    half_t* featT  = (half_t*)p;

    // ---- batch-independent precompute ----
    k_convert<<<dim3(768, 1, 3), 256, 0, stream>>>(att, Wq, V, atth, wqh, Vh);
    k_transp3<<<dim3(32, 32, 3), 256, 0, stream>>>(Wk, Wo, Wv, WkT, WoT, WvT);
    k_wobv<<<dim3(512), 256, 0, stream>>>(Wo, bv, Wobv);
    // prepA: z0 q = att@Wq.T + bq (f16);  z1 U = V@Wo (f16)
    {
        GDesc dq{atth, wqh, nullptr, qh, bq, LP, M_, 1, 0};
        GDesc dU{Vh, WoT, nullptr, Uh, nullptr, C_, M_, 1, 0};
        k_prep<<<dim3(8, 3, 2), 256, 0, stream>>>(dq, dU);
    }
    // prepB: z0 Qk = q@Wk -> rows 2s;  z1 Wv2 = U@Wv -> rows 2s+1
    {
        GDesc dk{qh, WkT, nullptr, AstackP, nullptr, M_, C_, 2, 0};
        GDesc dv{Uh, WvT, nullptr, AstackP, nullptr, M_, C_, 2, 1};
        k_prep<<<dim3(16, 3, 2), 256, 0, stream>>>(dk, dv);
    }

    // ---- main per-batch-split pipeline ----
    for (int h = 0; h < nsplit; ++h) {
        const float* fh = feat + (size_t)h * nB * C_ * N_;
        k_transf<<<dim3(4, 32, nB), 256, 0, stream>>>(fh, featT, poolp);
        k_poolv<<<dim3(4, nB), 256, 0, stream>>>(poolp, bo, Wobv, V, base2 + (size_t)h * nB * S_);
        k_fused<<<dim3(nB, 4), 256, 0, stream>>>(AstackP, featT, base2, out, h * nB);
    }
}

// Round 9
// 252.736 us; speedup vs baseline: 1.9471x; 1.0684x over previous
//
#include <hip/hip_runtime.h>
#include <hip/hip_bf16.h>
#include <cstdint>

typedef _Float16 half_t;
typedef _Float16 f16x8 __attribute__((ext_vector_type(8), aligned(16)));
typedef _Float16 f16x4 __attribute__((ext_vector_type(4), aligned(8)));
typedef _Float16 f16x2 __attribute__((ext_vector_type(2), aligned(4)));
typedef float f32x4 __attribute__((ext_vector_type(4)));

#define B_ 128
#define C_ 2048
#define N_ 196
#define S_ 312
#define L_ 300
#define LP 320   // padded L (10 x 32)
#define M_ 1024
#define NP 224   // padded N (14 x 16)
#define SP 384   // padded S for prep GEMMs (3 x 128)

// ---- async global->LDS, 16B per lane ----
__device__ __forceinline__ void gload16(const half_t* g, half_t* l) {
    __builtin_amdgcn_global_load_lds((const __attribute__((address_space(1))) void*)g,
                                     (__attribute__((address_space(3))) void*)l, 16, 0, 0);
}

// ---------------------------------------------------------------------------
// f32->f16 pad/convert + Wobv matvec:
// z0: att [312,300]->[384,320]; z1: Wq [1024,300]->[1024,320];
// z2: V_final [312,2048]->[384,2048]; z3: Wobv[c] = sum_m Wo[c][m]*bv[m].
// grid (768,1,4), block 256
__global__ __launch_bounds__(256) void k_convert(const float* __restrict__ att, const float* __restrict__ Wq,
                                                 const float* __restrict__ V, const float* __restrict__ Wo,
                                                 const float* __restrict__ bv, half_t* __restrict__ atth,
                                                 half_t* __restrict__ wqh, half_t* __restrict__ vh,
                                                 float* __restrict__ Wobv) {
    int z = blockIdx.z;
    if (z == 3) {
        if (blockIdx.x >= 512) return;
        int c = blockIdx.x * 4 + (threadIdx.x >> 6);
        int lane = threadIdx.x & 63;
        const float* wr_ = Wo + (size_t)c * M_;
        float acc = 0;
#pragma unroll
        for (int i = 0; i < 16; ++i) acc += wr_[lane + 64 * i] * bv[lane + 64 * i];
        for (int off = 32; off; off >>= 1) acc += __shfl_xor(acc, off);
        if (lane == 0) Wobv[c] = acc;
        return;
    }
    size_t e = ((size_t)blockIdx.x * 256 + threadIdx.x) * 4;
    if (z == 0) {
        if (e >= (size_t)SP * LP) return;
        int r = (int)(e / LP), c = (int)(e % LP);
        f16x4 h;
#pragma unroll
        for (int j = 0; j < 4; ++j) h[j] = (half_t)((r < S_ && c + j < L_) ? att[(size_t)r * L_ + c + j] : 0.f);
        *(f16x4*)&atth[e] = h;
    } else if (z == 1) {
        if (e >= (size_t)M_ * LP) return;
        int r = (int)(e / LP), c = (int)(e % LP);
        f16x4 h;
#pragma unroll
        for (int j = 0; j < 4; ++j) h[j] = (half_t)((c + j < L_) ? Wq[(size_t)r * L_ + c + j] : 0.f);
        *(f16x4*)&wqh[e] = h;
    } else {
        if (e >= (size_t)SP * C_) return;
        int r = (int)(e / C_);
        f16x4 h;
        if (r < S_) {
            float4 v = *(const float4*)&V[e];
            h[0] = (half_t)v.x; h[1] = (half_t)v.y; h[2] = (half_t)v.z; h[3] = (half_t)v.w;
        } else {
            h[0] = h[1] = h[2] = h[3] = (half_t)0.f;
        }
        *(f16x4*)&vh[e] = h;
    }
}

// ---------------------------------------------------------------------------
// Three transposes (f32 [R][Cc] -> f16 [Cc][R]) in one dispatch.
// z=0: Wk 1024x2048; z=1: Wo 2048x1024; z=2: Wv 1024x2048.  grid (32,32,3), block 256
__global__ __launch_bounds__(256) void k_transp3(const float* __restrict__ Wk, const float* __restrict__ Wo,
                                                 const float* __restrict__ Wv, half_t* __restrict__ WkT,
                                                 half_t* __restrict__ WoT, half_t* __restrict__ WvT) {
    __shared__ __attribute__((aligned(16))) half_t lsT[64][72];
    int z = blockIdx.z;
    const float* in; half_t* out; int R, Cc;
    if (z == 0)      { in = Wk; out = WkT; R = 1024; Cc = 2048; }
    else if (z == 1) { in = Wo; out = WoT; R = 2048; Cc = 1024; }
    else             { in = Wv; out = WvT; R = 1024; Cc = 2048; }
    if ((int)blockIdx.x >= Cc / 64 || (int)blockIdx.y >= R / 64) return;
    int c0 = blockIdx.x * 64, r0 = blockIdx.y * 64;
    int t = threadIdx.x;
#pragma unroll
    for (int i = 0; i < 4; ++i) {
        int Q = t + 256 * i;
        int rq = Q >> 5, cq = Q & 31;
        int rr = 2 * rq, cc = 2 * cq;
        const float* p0 = in + (size_t)(r0 + rr) * Cc + c0 + cc;
        float2 va = *(const float2*)p0;
        float2 vb = *(const float2*)(p0 + Cc);
        f16x2 w0; w0[0] = (half_t)va.x; w0[1] = (half_t)vb.x;
        f16x2 w1; w1[0] = (half_t)va.y; w1[1] = (half_t)vb.y;
        *(f16x2*)&lsT[cc][rr]     = w0;   // lsT[c][r] = in[r][c]
        *(f16x2*)&lsT[cc + 1][rr] = w1;
    }
    __syncthreads();
    int cl = t >> 2, ch = t & 3;
    f16x8 v0 = *(const f16x8*)&lsT[cl][ch * 16];
    f16x8 v1 = *(const f16x8*)&lsT[cl][ch * 16 + 8];
    half_t* po = out + (size_t)(c0 + cl) * R + r0 + ch * 16;
    *(f16x8*)po = v0;
    *(f16x8*)(po + 8) = v1;
}

// ---------------------------------------------------------------------------
// Dual-descriptor prep GEMM (counted-vmcnt 3-slot ring + XOR-swizzled LDS) — R5-proven.
// C[r][col] = sum_k A[r][k] * Bm[col][k]; out row = r*rowmul + rowoff.
struct GDesc {
    const half_t* A; const half_t* Bm;
    float* outF; half_t* outH; const float* bias;
    int kdim; int ldo; int rowmul; int rowoff;
};

__global__ __launch_bounds__(256) void k_prep(GDesc d0, GDesc d1) {
    GDesc d = blockIdx.z ? d1 : d0;
    __shared__ __attribute__((aligned(16))) half_t lsA[3][128 * 32];
    __shared__ __attribute__((aligned(16))) half_t lsB[3][128 * 32];
    int t = threadIdx.x;
    int wid = t >> 6, lane = t & 63;
    const int rA0 = blockIdx.y * 128, rB0 = blockIdx.x * 128;
    int wr = wid >> 1, wc = wid & 1;
    int g = lane >> 4, l15 = lane & 15;
    const int r_ = t >> 2;
    const int gsrc = ((t & 3) ^ ((t >> 3) & 3)) * 8;  // pre-swizzled source chunk
    const int kdim = d.kdim;
    const half_t* pA  = d.A + (size_t)(rA0 + r_) * kdim + gsrc;
    const half_t* pA2 = pA + (size_t)64 * kdim;
    const half_t* pB  = d.Bm + (size_t)(rB0 + r_) * kdim + gsrc;
    const half_t* pB2 = pB + (size_t)64 * kdim;
    const int lo = t * 8;
    const int xsw = ((l15 >> 1) & 3) * 8;
    f32x4 acc[4][4] = {};
    int nk = kdim >> 5;

#define STAGE(slot, kc)                              \
    do {                                             \
        gload16(pA + (kc), &lsA[slot][lo]);          \
        gload16(pA2 + (kc), &lsA[slot][lo + 2048]);  \
        gload16(pB + (kc), &lsB[slot][lo]);          \
        gload16(pB2 + (kc), &lsB[slot][lo + 2048]);  \
    } while (0)

    STAGE(0, 0);
    STAGE(1, 32);
    int cur = 0, nxt = 2;
    for (int tk = 0; tk < nk; ++tk) {
        if (tk == nk - 1) asm volatile("s_waitcnt vmcnt(0)" ::: "memory");
        else              asm volatile("s_waitcnt vmcnt(4)" ::: "memory");
        __builtin_amdgcn_s_barrier();
        __builtin_amdgcn_sched_barrier(0);
        f16x8 af[4], bf[4];
#pragma unroll
        for (int i = 0; i < 4; ++i) af[i] = *(const f16x8*)&lsA[cur][(wr * 64 + i * 16 + l15) * 32 + ((g * 8) ^ xsw)];
#pragma unroll
        for (int j = 0; j < 4; ++j) bf[j] = *(const f16x8*)&lsB[cur][(wc * 64 + j * 16 + l15) * 32 + ((g * 8) ^ xsw)];
        if (tk + 2 < nk) STAGE(nxt, (tk + 2) * 32);
#pragma unroll
        for (int i = 0; i < 4; ++i)
#pragma unroll
            for (int j = 0; j < 4; ++j)
                acc[i][j] = __builtin_amdgcn_mfma_f32_16x16x32_f16(af[i], bf[j], acc[i][j], 0, 0, 0);
        cur = (cur == 2) ? 0 : cur + 1;
        nxt = (nxt == 2) ? 0 : nxt + 1;
    }
#undef STAGE

#pragma unroll
    for (int i = 0; i < 4; ++i) {
        int r0 = rA0 + wr * 64 + i * 16 + g * 4;
#pragma unroll
        for (int j = 0; j < 4; ++j) {
            int c0 = rB0 + wc * 64 + j * 16 + l15;
            float bval = d.bias ? d.bias[c0] : 0.f;
#pragma unroll
            for (int qq = 0; qq < 4; ++qq) {
                int rr = (r0 + qq) * d.rowmul + d.rowoff;
                float val = acc[i][j][qq];
                if (d.outF) d.outF[(size_t)rr * d.ldo + c0] = val;
                if (d.outH) d.outH[(size_t)rr * d.ldo + c0] = (half_t)(val + bval);
            }
        }
    }
}

// ---------------------------------------------------------------------------
// Fused main kernel — 160-row tile, grid 512 = 2 blocks/CU, asymmetric counted ring:
// A 2-slot (24 KB), B 3-slot (48 KB) -> 74.6 KB total, 2 blocks/CU preserved.
// Per iter tk: VMEM queue = [B(tk) 4, A(tk) 3, B(tk+1) 4]; vmcnt(4) certifies
// A(tk)+B(tk) landed while B(tk+1) stays in flight (never drain; T4).
// Issue order in body: A(tk+1) then B(tk+2).  WAR: A slot alternates (reads of
// the overwritten slot drained last iter); B slot (tk+2)%3 last read iter tk-1,
// drained by that iter's lgkmcnt(0) before its barrier.
// AstackP rows interleaved: 2s = Qk_s, 2s+1 = Wv2_s.  Block (bb, st): s in
// [st*80, st*80+80), all 224 cols.  4 waves 2x2; wave = 80 rows x 112 cols.
__global__ __launch_bounds__(256) void k_fused(const half_t* __restrict__ AstackP, const half_t* __restrict__ featT,
                                               const float* __restrict__ base2, float* __restrict__ out, int b0) {
    __shared__ __attribute__((aligned(16))) half_t lsA[2][192 * 32];
    __shared__ __attribute__((aligned(16))) half_t lsB[3][256 * 32];
    __shared__ float lsE[2][80][4];
    int t = threadIdx.x;
    int bb = blockIdx.x, st = blockIdx.y;
    int wid = t >> 6, lane = t & 63;
    int wr = wid >> 1, wc = wid & 1;
    int g = lane >> 4, l15 = lane & 15;
    const int gsrc = ((t & 3) ^ ((t >> 3) & 3)) * 8;
    // A: stage 192 rows (rows >=160 unused; AstackP has 768 rows so in-bounds for st=3)
    const half_t* pA  = AstackP + ((size_t)st * 160 + (t >> 2)) * C_ + gsrc;
    const half_t* pA2 = pA + (size_t)64 * C_;
    const half_t* pA3 = pA + (size_t)128 * C_;
    // B: stage 256 rows (32 over-stage; ws has +128KB slack for bb=127)
    const half_t* pB  = featT + ((size_t)bb * NP + (t >> 2)) * C_ + gsrc;
    const half_t* pB2 = pB + (size_t)64 * C_;
    const half_t* pB3 = pB + (size_t)128 * C_;
    const half_t* pB4 = pB + (size_t)192 * C_;
    const int lo = t * 8;
    const int xsw = ((l15 >> 1) & 3) * 8;
    f32x4 acc[5][7] = {};

#define FSTAGEA(slot, kc)                            \
    do {                                             \
        gload16(pA + (kc), &lsA[slot][lo]);          \
        gload16(pA2 + (kc), &lsA[slot][lo + 2048]);  \
        gload16(pA3 + (kc), &lsA[slot][lo + 4096]);  \
    } while (0)
#define FSTAGEB(slot, kc)                            \
    do {                                             \
        gload16(pB + (kc), &lsB[slot][lo]);          \
        gload16(pB2 + (kc), &lsB[slot][lo + 2048]);  \
        gload16(pB3 + (kc), &lsB[slot][lo + 4096]);  \
        gload16(pB4 + (kc), &lsB[slot][lo + 6144]);  \
    } while (0)

    // prologue: queue = [A(0) 3, B(0) 4, B(1) 4]
    FSTAGEA(0, 0);
    FSTAGEB(0, 0);
    FSTAGEB(1, 32);
    for (int tk = 0; tk < 64; ++tk) {
        int ca = tk & 1;
        int cb = tk % 3;
        if (tk == 63) asm volatile("s_waitcnt vmcnt(0)" ::: "memory");
        else          asm volatile("s_waitcnt vmcnt(4)" ::: "memory");
        __builtin_amdgcn_s_barrier();
        __builtin_amdgcn_sched_barrier(0);
        if (tk + 1 < 64) FSTAGEA(ca ^ 1, (tk + 1) * 32);
        if (tk + 2 < 64) FSTAGEB((tk + 2) % 3, (tk + 2) * 32);
        f16x8 af[5], bf[7];
#pragma unroll
        for (int i = 0; i < 5; ++i) af[i] = *(const f16x8*)&lsA[ca][(wr * 80 + i * 16 + l15) * 32 + ((g * 8) ^ xsw)];
#pragma unroll
        for (int j = 0; j < 7; ++j) bf[j] = *(const f16x8*)&lsB[cb][(wc * 112 + j * 16 + l15) * 32 + ((g * 8) ^ xsw)];
        asm volatile("s_waitcnt lgkmcnt(0)" ::: "memory"); // my reads done before MFMA & next barrier
        __builtin_amdgcn_sched_barrier(0);
#pragma unroll
        for (int i = 0; i < 5; ++i)
#pragma unroll
            for (int j = 0; j < 7; ++j)
                acc[i][j] = __builtin_amdgcn_mfma_f32_16x16x32_f16(af[i], bf[j], acc[i][j], 0, 0, 0);
    }
#undef FSTAGEA
#undef FSTAGEB

    // ---- epilogue: per s-row softmax over n + dot with W2 ----
    // lane's acc[i][j][qq]: row = wr*80+i*16+g*4+qq (even=score 2s, odd=W2 2s+1),
    //                       col = wc*112+j*16+l15.
#pragma unroll
    for (int i = 0; i < 5; ++i) {
#pragma unroll
        for (int pair = 0; pair < 2; ++pair) {
            float m = -3.0e38f;
#pragma unroll
            for (int j = 0; j < 7; ++j) {
                int col = wc * 112 + j * 16 + l15;
                if (col < N_) m = fmaxf(m, acc[i][j][2 * pair]);
            }
#pragma unroll
            for (int off = 1; off < 16; off <<= 1) m = fmaxf(m, __shfl_xor(m, off));
            float ls = 0.f, dt = 0.f;
#pragma unroll
            for (int j = 0; j < 7; ++j) {
                int col = wc * 112 + j * 16 + l15;
                if (col < N_) {
                    float p = __expf(acc[i][j][2 * pair] - m);
                    ls += p;
                    dt += p * acc[i][j][2 * pair + 1];
                }
            }
#pragma unroll
            for (int off = 1; off < 16; off <<= 1) { ls += __shfl_xor(ls, off); dt += __shfl_xor(dt, off); }
            if (l15 == 0) {
                int pr = wr * 40 + i * 8 + g * 2 + pair;
                lsE[wc][pr][0] = m; lsE[wc][pr][1] = ls; lsE[wc][pr][2] = dt;
            }
        }
    }
    __syncthreads();
    if (t < 80) {
        float m0 = lsE[0][t][0], l0 = lsE[0][t][1], dv0 = lsE[0][t][2];
        float m1 = lsE[1][t][0], l1 = lsE[1][t][1], dv1 = lsE[1][t][2];
        float M = fmaxf(m0, m1);
        float e0 = __expf(m0 - M), e1 = __expf(m1 - M);
        float L = l0 * e0 + l1 * e1, D = dv0 * e0 + dv1 * e1;
        int s = st * 80 + t;
        if (s < S_) {
            int bg = b0 + bb;
            out[(size_t)bg * S_ + s] = base2[(size_t)bg * S_ + s] + D / L;
        }
    }
}

// ---------------------------------------------------------------------------
// feat [nB][2048][196] f32 -> featT [(bb*224 + n)][2048] f16 (n zero-padded to 224)
// PLUS fused pool partials.  grid (4 nT, 32 cT, nB), block 256
__global__ __launch_bounds__(256) void k_transf(const float* __restrict__ feat, half_t* __restrict__ featT,
                                                float* __restrict__ poolp) {
    __shared__ __attribute__((aligned(16))) half_t lsT[64][72];
    __shared__ float poolLs[64];
    int nT = blockIdx.x, cT = blockIdx.y, bb = blockIdx.z;
    int n0 = nT * 64, c0 = cT * 64;
    const float* fb = feat + (size_t)bb * C_ * N_;
    int t = threadIdx.x;
#pragma unroll
    for (int i = 0; i < 4; ++i) {
        int Q = t + 256 * i;
        int cq = Q >> 5, nq = Q & 31;
        int cc = 2 * cq, nn = 2 * nq;
        int n = n0 + nn;
        float2 va = {0, 0}, vb = {0, 0};
        if (n < N_) {
            const float* p0 = fb + (size_t)(c0 + cc) * N_ + n;
            va = *(const float2*)p0;
            vb = *(const float2*)(p0 + N_);
        }
        f16x2 w0; w0[0] = (half_t)va.x; w0[1] = (half_t)vb.x;
        f16x2 w1; w1[0] = (half_t)va.y; w1[1] = (half_t)vb.y;
        *(f16x2*)&lsT[nn][cc]     = w0;   // lsT[n][c]
        *(f16x2*)&lsT[nn + 1][cc] = w1;
        float sA = va.x + va.y, sB = vb.x + vb.y;
        for (int off = 16; off; off >>= 1) { sA += __shfl_xor(sA, off); sB += __shfl_xor(sB, off); }
        if ((t & 31) == 0) { poolLs[cc] = sA; poolLs[cc + 1] = sB; }
    }
    __syncthreads();
    int nl = t >> 2, ch = t & 3;
    int n = n0 + nl;
    if (n < NP) {
        f16x8 v0 = *(const f16x8*)&lsT[nl][ch * 16];
        f16x8 v1 = *(const f16x8*)&lsT[nl][ch * 16 + 8];
        half_t* po = featT + ((size_t)bb * NP + n) * C_ + c0 + ch * 16;
        *(f16x8*)po = v0;
        *(f16x8*)(po + 8) = v1;
    }
    if (t < 64) poolp[((size_t)nT * B_ + bb) * C_ + c0 + t] = poolLs[t];
}

// ---------------------------------------------------------------------------
// base2[b][s] = sum_c (mean_pool[b][c] + bo[c] + Wobv[c]) * V[s][c]  (ubv folded in).
// grid (4 sc, nB b), block 256
__global__ __launch_bounds__(256) void k_poolv(const float* __restrict__ poolp, const float* __restrict__ bo,
                                               const float* __restrict__ Wobv, const float* __restrict__ V,
                                               float* __restrict__ base2) {
    int sc = blockIdx.x, b = blockIdx.y;
    __shared__ float w[C_];
    int t = threadIdx.x;
    for (int i = t; i < C_; i += 256) {
        float s = poolp[(size_t)b * C_ + i] + poolp[((size_t)B_ + b) * C_ + i] +
                  poolp[((size_t)2 * B_ + b) * C_ + i] + poolp[((size_t)3 * B_ + b) * C_ + i];
        w[i] = s * (1.0f / 196.0f) + bo[i] + Wobv[i];
    }
    __syncthreads();
    int wid = t >> 6, lane = t & 63;
    for (int s = sc * 78 + wid; s < sc * 78 + 78; s += 4) {
        const float* vr = V + (size_t)s * C_;
        float acc = 0;
#pragma unroll
        for (int i = 0; i < 32; ++i) acc += w[lane + 64 * i] * vr[lane + 64 * i];
        for (int off = 32; off; off >>= 1) acc += __shfl_xor(acc, off);
        if (lane == 0) base2[(size_t)b * S_ + s] = acc;
    }
}

// ---------------------------------------------------------------------------
extern "C" void kernel_launch(void* const* d_in, const int* in_sizes, int n_in,
                              void* d_out, int out_size, void* d_ws, size_t ws_size,
                              hipStream_t stream) {
    const float* feat = (const float*)d_in[0];
    const float* att  = (const float*)d_in[1];
    const float* Wq   = (const float*)d_in[2];
    const float* bq   = (const float*)d_in[3];
    const float* Wk   = (const float*)d_in[4];
    /* bk = d_in[5] — per-s constant over n in scores: softmax-invariant, dropped */
    const float* Wv   = (const float*)d_in[6];
    const float* bv   = (const float*)d_in[7];
    const float* Wo   = (const float*)d_in[8];
    const float* bo   = (const float*)d_in[9];
    const float* V    = (const float*)d_in[10];
    float* out = (float*)d_out;

    auto AL = [](size_t x) { return (x + 255) & ~(size_t)255; };
    const size_t szAstk = (size_t)768 * C_ * 2;       // pair-interleaved [2s | 2s+1]
    const size_t szQh   = (size_t)SP * M_ * 2;
    const size_t szVh   = (size_t)SP * C_ * 2;
    const size_t szUh   = (size_t)SP * M_ * 2;
    const size_t szWT   = (size_t)C_ * M_ * 2;
    const size_t szAtth = (size_t)SP * LP * 2;
    const size_t szWqh  = (size_t)M_ * LP * 2;
    const size_t szPoolp = (size_t)4 * B_ * C_ * 4;
    const size_t szBase = (size_t)B_ * S_ * 4;
    const size_t szWobv = (size_t)C_ * 4;
    size_t fixed = AL(szAstk) + AL(szQh) + AL(szVh) + AL(szUh) + 3 * AL(szWT) +
                   AL(szAtth) + AL(szWqh) + AL(szPoolp) + AL(szBase) + AL(szWobv);

    int nsplit = 1;
    while (nsplit < 32) {
        size_t nB = B_ / nsplit;
        size_t need = fixed + AL(nB * NP * C_ * 2 + 131072);  // +128KB over-stage slack
        if (need <= ws_size) break;
        nsplit *= 2;
    }
    int nB = B_ / nsplit;

    char* p = (char*)d_ws;
    half_t* AstackP = (half_t*)p; p += AL(szAstk);
    half_t* qh     = (half_t*)p; p += AL(szQh);
    half_t* Vh     = (half_t*)p; p += AL(szVh);
    half_t* Uh     = (half_t*)p; p += AL(szUh);
    half_t* WkT    = (half_t*)p; p += AL(szWT);
    half_t* WoT    = (half_t*)p; p += AL(szWT);
    half_t* WvT    = (half_t*)p; p += AL(szWT);
    half_t* atth   = (half_t*)p; p += AL(szAtth);
    half_t* wqh    = (half_t*)p; p += AL(szWqh);
    float*  poolp  = (float*)p;  p += AL(szPoolp);
    float*  base2  = (float*)p;  p += AL(szBase);
    float*  Wobv   = (float*)p;  p += AL(szWobv);
    half_t* featT  = (half_t*)p;

    // ---- batch-independent precompute ----
    k_convert<<<dim3(768, 1, 4), 256, 0, stream>>>(att, Wq, V, Wo, bv, atth, wqh, Vh, Wobv);
    k_transp3<<<dim3(32, 32, 3), 256, 0, stream>>>(Wk, Wo, Wv, WkT, WoT, WvT);
    // prepA: z0 q = att@Wq.T + bq (f16);  z1 U = V@Wo (f16)
    {
        GDesc dq{atth, wqh, nullptr, qh, bq, LP, M_, 1, 0};
        GDesc dU{Vh, WoT, nullptr, Uh, nullptr, C_, M_, 1, 0};
        k_prep<<<dim3(8, 3, 2), 256, 0, stream>>>(dq, dU);
    }
    // prepB: z0 Qk = q@Wk -> rows 2s;  z1 Wv2 = U@Wv -> rows 2s+1
    {
        GDesc dk{qh, WkT, nullptr, AstackP, nullptr, M_, C_, 2, 0};
        GDesc dv{Uh, WvT, nullptr, AstackP, nullptr, M_, C_, 2, 1};
        k_prep<<<dim3(16, 3, 2), 256, 0, stream>>>(dk, dv);
    }

    // ---- main per-batch-split pipeline ----
    for (int h = 0; h < nsplit; ++h) {
        const float* fh = feat + (size_t)h * nB * C_ * N_;
        k_transf<<<dim3(4, 32, nB), 256, 0, stream>>>(fh, featT, poolp);
        k_poolv<<<dim3(4, nB), 256, 0, stream>>>(poolp, bo, Wobv, V, base2 + (size_t)h * nB * S_);
        k_fused<<<dim3(nB, 4), 256, 0, stream>>>(AstackP, featT, base2, out, h * nB);
    }
}

// Round 10
// 218.050 us; speedup vs baseline: 2.2569x; 1.1591x over previous
//
#include <hip/hip_runtime.h>
#include <hip/hip_bf16.h>
#include <cstdint>

typedef _Float16 half_t;
typedef _Float16 f16x8 __attribute__((ext_vector_type(8), aligned(16)));
typedef _Float16 f16x4 __attribute__((ext_vector_type(4), aligned(8)));
typedef _Float16 f16x2 __attribute__((ext_vector_type(2), aligned(4)));
typedef float f32x4 __attribute__((ext_vector_type(4)));

#define B_ 128
#define C_ 2048
#define N_ 196
#define S_ 312
#define L_ 300
#define LP 320   // padded L (10 x 32)
#define M_ 1024
#define NP 224   // padded N (14 x 16)
#define SP 384   // padded S for prep GEMMs (3 x 128)

// ---- async global->LDS, 16B per lane ----
__device__ __forceinline__ void gload16(const half_t* g, half_t* l) {
    __builtin_amdgcn_global_load_lds((const __attribute__((address_space(1))) void*)g,
                                     (__attribute__((address_space(3))) void*)l, 16, 0, 0);
}

struct GDesc {
    const half_t* A; const half_t* Bm;
    float* outF; half_t* outH; const float* bias;
    int kdim; int ldo; int rowmul; int rowoff;
};

// ===========================================================================
// Device role bodies (shared by umbrella + legacy kernels)
// ===========================================================================

// ---- convert/pad + Wobv: role index c in [0,1720) ----
__device__ __forceinline__ void dev_convert(int c, int t, const float* __restrict__ att,
                                            const float* __restrict__ Wq, const float* __restrict__ V,
                                            const float* __restrict__ Wo, const float* __restrict__ bv,
                                            half_t* __restrict__ atth, half_t* __restrict__ wqh,
                                            half_t* __restrict__ vh, float* __restrict__ Wobv) {
    if (c < 120) {            // att [312,300] -> [384,320]
        size_t e = ((size_t)c * 256 + t) * 4;
        int r = (int)(e / LP), cc = (int)(e % LP);
        f16x4 h;
#pragma unroll
        for (int j = 0; j < 4; ++j) h[j] = (half_t)((r < S_ && cc + j < L_) ? att[(size_t)r * L_ + cc + j] : 0.f);
        *(f16x4*)&atth[e] = h;
    } else if (c < 440) {     // Wq [1024,300] -> [1024,320]
        size_t e = ((size_t)(c - 120) * 256 + t) * 4;
        int r = (int)(e / LP), cc = (int)(e % LP);
        f16x4 h;
#pragma unroll
        for (int j = 0; j < 4; ++j) h[j] = (half_t)((cc + j < L_) ? Wq[(size_t)r * L_ + cc + j] : 0.f);
        *(f16x4*)&wqh[e] = h;
    } else if (c < 1208) {    // V [312,2048] -> [384,2048]
        size_t e = ((size_t)(c - 440) * 256 + t) * 4;
        int r = (int)(e / C_);
        f16x4 h;
        if (r < S_) {
            float4 v = *(const float4*)&V[e];
            h[0] = (half_t)v.x; h[1] = (half_t)v.y; h[2] = (half_t)v.z; h[3] = (half_t)v.w;
        } else {
            h[0] = h[1] = h[2] = h[3] = (half_t)0.f;
        }
        *(f16x4*)&vh[e] = h;
    } else {                  // Wobv[cc] = sum_m Wo[cc][m]*bv[m]
        int cc = (c - 1208) * 4 + (t >> 6);
        int lane = t & 63;
        const float* wr_ = Wo + (size_t)cc * M_;
        float acc = 0;
#pragma unroll
        for (int i = 0; i < 16; ++i) acc += wr_[lane + 64 * i] * bv[lane + 64 * i];
        for (int off = 32; off; off >>= 1) acc += __shfl_xor(acc, off);
        if (lane == 0) Wobv[cc] = acc;
    }
}

// ---- weight transposes: role index r3 in [0,1536) ----
__device__ __forceinline__ void dev_transp3(int r3, int t, const float* __restrict__ Wk,
                                            const float* __restrict__ Wo, const float* __restrict__ Wv,
                                            half_t* __restrict__ WkT, half_t* __restrict__ WoT,
                                            half_t* __restrict__ WvT, char* smc) {
    half_t (*lsT)[72] = (half_t(*)[72])smc;
    int z = r3 >> 9, r = r3 & 511;
    const float* in; half_t* out; int R, Cc, bx, by;
    if (z == 0)      { in = Wk; out = WkT; R = 1024; Cc = 2048; bx = r & 31; by = r >> 5; }
    else if (z == 1) { in = Wo; out = WoT; R = 2048; Cc = 1024; bx = r & 15; by = r >> 4; }
    else             { in = Wv; out = WvT; R = 1024; Cc = 2048; bx = r & 31; by = r >> 5; }
    int c0 = bx * 64, r0 = by * 64;
#pragma unroll
    for (int i = 0; i < 4; ++i) {
        int Q = t + 256 * i;
        int rq = Q >> 5, cq = Q & 31;
        int rr = 2 * rq, cc = 2 * cq;
        const float* p0 = in + (size_t)(r0 + rr) * Cc + c0 + cc;
        float2 va = *(const float2*)p0;
        float2 vb = *(const float2*)(p0 + Cc);
        f16x2 w0; w0[0] = (half_t)va.x; w0[1] = (half_t)vb.x;
        f16x2 w1; w1[0] = (half_t)va.y; w1[1] = (half_t)vb.y;
        *(f16x2*)&lsT[cc][rr]     = w0;   // lsT[c][r] = in[r][c]
        *(f16x2*)&lsT[cc + 1][rr] = w1;
    }
    __syncthreads();
    int cl = t >> 2, ch = t & 3;
    f16x8 v0 = *(const f16x8*)&lsT[cl][ch * 16];
    f16x8 v1 = *(const f16x8*)&lsT[cl][ch * 16 + 8];
    half_t* po = out + (size_t)(c0 + cl) * R + r0 + ch * 16;
    *(f16x8*)po = v0;
    *(f16x8*)(po + 8) = v1;
}

// ---- feat transpose+convert + pool partials ----
__device__ __forceinline__ void dev_transf(const float* __restrict__ feat, half_t* __restrict__ featT,
                                           float* __restrict__ poolp, int nT, int cT, int bb, int t, char* smc) {
    half_t (*lsT)[72] = (half_t(*)[72])smc;
    float* poolLs = (float*)(smc + 64 * 72 * 2);
    int n0 = nT * 64, c0 = cT * 64;
    const float* fb = feat + (size_t)bb * C_ * N_;
#pragma unroll
    for (int i = 0; i < 4; ++i) {
        int Q = t + 256 * i;
        int cq = Q >> 5, nq = Q & 31;
        int cc = 2 * cq, nn = 2 * nq;
        int n = n0 + nn;
        float2 va = {0, 0}, vb = {0, 0};
        if (n < N_) {
            const float* p0 = fb + (size_t)(c0 + cc) * N_ + n;
            va = *(const float2*)p0;
            vb = *(const float2*)(p0 + N_);
        }
        f16x2 w0; w0[0] = (half_t)va.x; w0[1] = (half_t)vb.x;
        f16x2 w1; w1[0] = (half_t)va.y; w1[1] = (half_t)vb.y;
        *(f16x2*)&lsT[nn][cc]     = w0;   // lsT[n][c]
        *(f16x2*)&lsT[nn + 1][cc] = w1;
        float sA = va.x + va.y, sB = vb.x + vb.y;
        for (int off = 16; off; off >>= 1) { sA += __shfl_xor(sA, off); sB += __shfl_xor(sB, off); }
        if ((t & 31) == 0) { poolLs[cc] = sA; poolLs[cc + 1] = sB; }
    }
    __syncthreads();
    int nl = t >> 2, ch = t & 3;
    int n = n0 + nl;
    if (n < NP) {   // rows [224,256) of nT=3 must NOT spill into the next batch's tile
        f16x8 v0 = *(const f16x8*)&lsT[nl][ch * 16];
        f16x8 v1 = *(const f16x8*)&lsT[nl][ch * 16 + 8];
        half_t* po = featT + ((size_t)bb * NP + n) * C_ + c0 + ch * 16;
        *(f16x8*)po = v0;
        *(f16x8*)(po + 8) = v1;
    }
    if (t < 64) poolp[((size_t)nT * B_ + bb) * C_ + c0 + t] = poolLs[t];
}

// ---- prep GEMM (counted-vmcnt 3-slot ring + XOR-swizzled LDS), R5-proven body ----
__device__ __forceinline__ void dev_prep(GDesc d, int bx, int by, int t, char* smc) {
    half_t* lsA = (half_t*)smc;            // 3 slots x 4096 halves
    half_t* lsB = lsA + 3 * 4096;
    int wid = t >> 6, lane = t & 63;
    const int rA0 = by * 128, rB0 = bx * 128;
    int wr = wid >> 1, wc = wid & 1;
    int g = lane >> 4, l15 = lane & 15;
    const int r_ = t >> 2;
    const int gsrc = ((t & 3) ^ ((t >> 3) & 3)) * 8;
    const int kdim = d.kdim;
    const half_t* pA  = d.A + (size_t)(rA0 + r_) * kdim + gsrc;
    const half_t* pA2 = pA + (size_t)64 * kdim;
    const half_t* pB  = d.Bm + (size_t)(rB0 + r_) * kdim + gsrc;
    const half_t* pB2 = pB + (size_t)64 * kdim;
    const int lo = t * 8;
    const int xsw = ((l15 >> 1) & 3) * 8;
    f32x4 acc[4][4] = {};
    int nk = kdim >> 5;

#define PSTAGE(slot, kc)                                    \
    do {                                                    \
        gload16(pA + (kc), &lsA[(slot) * 4096 + lo]);       \
        gload16(pA2 + (kc), &lsA[(slot) * 4096 + lo + 2048]); \
        gload16(pB + (kc), &lsB[(slot) * 4096 + lo]);       \
        gload16(pB2 + (kc), &lsB[(slot) * 4096 + lo + 2048]); \
    } while (0)

    PSTAGE(0, 0);
    PSTAGE(1, 32);
    int cur = 0, nxt = 2;
    for (int tk = 0; tk < nk; ++tk) {
        if (tk == nk - 1) asm volatile("s_waitcnt vmcnt(0)" ::: "memory");
        else              asm volatile("s_waitcnt vmcnt(4)" ::: "memory");
        __builtin_amdgcn_s_barrier();
        __builtin_amdgcn_sched_barrier(0);
        f16x8 af[4], bf[4];
#pragma unroll
        for (int i = 0; i < 4; ++i) af[i] = *(const f16x8*)&lsA[cur * 4096 + (wr * 64 + i * 16 + l15) * 32 + ((g * 8) ^ xsw)];
#pragma unroll
        for (int j = 0; j < 4; ++j) bf[j] = *(const f16x8*)&lsB[cur * 4096 + (wc * 64 + j * 16 + l15) * 32 + ((g * 8) ^ xsw)];
        if (tk + 2 < nk) PSTAGE(nxt, (tk + 2) * 32);
#pragma unroll
        for (int i = 0; i < 4; ++i)
#pragma unroll
            for (int j = 0; j < 4; ++j)
                acc[i][j] = __builtin_amdgcn_mfma_f32_16x16x32_f16(af[i], bf[j], acc[i][j], 0, 0, 0);
        cur = (cur == 2) ? 0 : cur + 1;
        nxt = (nxt == 2) ? 0 : nxt + 1;
    }
#undef PSTAGE

#pragma unroll
    for (int i = 0; i < 4; ++i) {
        int r0 = rA0 + wr * 64 + i * 16 + g * 4;
#pragma unroll
        for (int j = 0; j < 4; ++j) {
            int c0 = rB0 + wc * 64 + j * 16 + l15;
            float bval = d.bias ? d.bias[c0] : 0.f;
#pragma unroll
            for (int qq = 0; qq < 4; ++qq) {
                int rr = (r0 + qq) * d.rowmul + d.rowoff;
                float val = acc[i][j][qq];
                if (d.outF) d.outF[(size_t)rr * d.ldo + c0] = val;
                if (d.outH) d.outH[(size_t)rr * d.ldo + c0] = (half_t)(val + bval);
            }
        }
    }
}

// ---- pool+V dot: base2[b][s] = sum_c (pool[b][c]+bo[c]+Wobv[c]) * V[s][c] ----
__device__ __forceinline__ void dev_poolv(const float* __restrict__ poolp, const float* __restrict__ bo,
                                          const float* __restrict__ Wobv, const float* __restrict__ V,
                                          float* __restrict__ base2, int sc, int b, int t, char* smc) {
    float* w = (float*)smc;
    for (int i = t; i < C_; i += 256) {
        float s = poolp[(size_t)b * C_ + i] + poolp[((size_t)B_ + b) * C_ + i] +
                  poolp[((size_t)2 * B_ + b) * C_ + i] + poolp[((size_t)3 * B_ + b) * C_ + i];
        w[i] = s * (1.0f / 196.0f) + bo[i] + Wobv[i];
    }
    __syncthreads();
    int wid = t >> 6, lane = t & 63;
    for (int s = sc * 78 + wid; s < sc * 78 + 78; s += 4) {
        const float* vr = V + (size_t)s * C_;
        float acc = 0;
#pragma unroll
        for (int i = 0; i < 32; ++i) acc += w[lane + 64 * i] * vr[lane + 64 * i];
        for (int off = 32; off; off >>= 1) acc += __shfl_xor(acc, off);
        if (lane == 0) base2[(size_t)b * S_ + s] = acc;
    }
}

// ===========================================================================
// Umbrella dispatches
// ===========================================================================

// D1: transf (16384) | convert+Wobv (1720) | transp3 (1536).  grid 19640, block 256
__global__ __launch_bounds__(256) void k_d1(const float* __restrict__ feat, const float* __restrict__ att,
                                            const float* __restrict__ Wq, const float* __restrict__ V,
                                            const float* __restrict__ Wo, const float* __restrict__ bv,
                                            const float* __restrict__ Wk, const float* __restrict__ Wv,
                                            half_t* __restrict__ featT, float* __restrict__ poolp,
                                            half_t* __restrict__ atth, half_t* __restrict__ wqh,
                                            half_t* __restrict__ vh, float* __restrict__ Wobv,
                                            half_t* __restrict__ WkT, half_t* __restrict__ WoT,
                                            half_t* __restrict__ WvT) {
    __shared__ __attribute__((aligned(16))) char sm[9472];
    int x = blockIdx.x, t = threadIdx.x;
    if (x < 16384) {
        dev_transf(feat, featT, poolp, x & 3, (x >> 2) & 31, x >> 7, t, sm);
    } else if (x < 16384 + 1720) {
        dev_convert(x - 16384, t, att, Wq, V, Wo, bv, atth, wqh, vh, Wobv);
    } else {
        dev_transp3(x - 16384 - 1720, t, Wk, Wo, Wv, WkT, WoT, WvT, sm);
    }
}

// D2: prepA (48: q & U GEMMs) | poolv (512).  grid 560, block 256
__global__ __launch_bounds__(256) void k_d2(GDesc dq, GDesc dU, const float* __restrict__ poolp,
                                            const float* __restrict__ bo, const float* __restrict__ Wobv,
                                            const float* __restrict__ V, float* __restrict__ base2) {
    __shared__ __attribute__((aligned(16))) char sm[49152];
    int x = blockIdx.x, t = threadIdx.x;
    if (x < 48) {
        dev_prep((x / 24) ? dU : dq, x & 7, (x >> 3) % 3, t, sm);
    } else {
        int r = x - 48;
        dev_poolv(poolp, bo, Wobv, V, base2, r & 3, r >> 2, t, sm);
    }
}

// D3 (and legacy prep): dual-descriptor prep GEMM.  grid (gx,3,2)
__global__ __launch_bounds__(256) void k_prep2(GDesc d0, GDesc d1) {
    __shared__ __attribute__((aligned(16))) char sm[49152];
    dev_prep(blockIdx.z ? d1 : d0, blockIdx.x, blockIdx.y, threadIdx.x, sm);
}

// Legacy helpers (nsplit > 1 fallback)
__global__ __launch_bounds__(256) void k_misc(const float* att, const float* Wq, const float* V,
                                              const float* Wo, const float* bv, const float* Wk,
                                              const float* Wv, half_t* atth, half_t* wqh, half_t* vh,
                                              float* Wobv, half_t* WkT, half_t* WoT, half_t* WvT) {
    __shared__ __attribute__((aligned(16))) char sm[9472];
    int x = blockIdx.x, t = threadIdx.x;
    if (x < 1720) dev_convert(x, t, att, Wq, V, Wo, bv, atth, wqh, vh, Wobv);
    else          dev_transp3(x - 1720, t, Wk, Wo, Wv, WkT, WoT, WvT, sm);
}
__global__ __launch_bounds__(256) void k_transf_only(const float* feat, half_t* featT, float* poolp) {
    __shared__ __attribute__((aligned(16))) char sm[9472];
    dev_transf(feat, featT, poolp, blockIdx.x, blockIdx.y, blockIdx.z, threadIdx.x, sm);
}
__global__ __launch_bounds__(256) void k_poolv_only(const float* poolp, const float* bo, const float* Wobv,
                                                    const float* V, float* base2) {
    __shared__ __attribute__((aligned(16))) char sm[8192];
    dev_poolv(poolp, bo, Wobv, V, base2, blockIdx.x, blockIdx.y, threadIdx.x, sm);
}

// ===========================================================================
// D4: fused main kernel — unchanged from R9 (160-row tile, asymmetric counted ring)
// ===========================================================================
__global__ __launch_bounds__(256) void k_fused(const half_t* __restrict__ AstackP, const half_t* __restrict__ featT,
                                               const float* __restrict__ base2, float* __restrict__ out, int b0) {
    __shared__ __attribute__((aligned(16))) half_t lsA[2][192 * 32];
    __shared__ __attribute__((aligned(16))) half_t lsB[3][256 * 32];
    __shared__ float lsE[2][80][4];
    int t = threadIdx.x;
    int bb = blockIdx.x, st = blockIdx.y;
    int wid = t >> 6, lane = t & 63;
    int wr = wid >> 1, wc = wid & 1;
    int g = lane >> 4, l15 = lane & 15;
    const int gsrc = ((t & 3) ^ ((t >> 3) & 3)) * 8;
    const half_t* pA  = AstackP + ((size_t)st * 160 + (t >> 2)) * C_ + gsrc;
    const half_t* pA2 = pA + (size_t)64 * C_;
    const half_t* pA3 = pA + (size_t)128 * C_;
    const half_t* pB  = featT + ((size_t)bb * NP + (t >> 2)) * C_ + gsrc;
    const half_t* pB2 = pB + (size_t)64 * C_;
    const half_t* pB3 = pB + (size_t)128 * C_;
    const half_t* pB4 = pB + (size_t)192 * C_;
    const int lo = t * 8;
    const int xsw = ((l15 >> 1) & 3) * 8;
    f32x4 acc[5][7] = {};

#define FSTAGEA(slot, kc)                            \
    do {                                             \
        gload16(pA + (kc), &lsA[slot][lo]);          \
        gload16(pA2 + (kc), &lsA[slot][lo + 2048]);  \
        gload16(pA3 + (kc), &lsA[slot][lo + 4096]);  \
    } while (0)
#define FSTAGEB(slot, kc)                            \
    do {                                             \
        gload16(pB + (kc), &lsB[slot][lo]);          \
        gload16(pB2 + (kc), &lsB[slot][lo + 2048]);  \
        gload16(pB3 + (kc), &lsB[slot][lo + 4096]);  \
        gload16(pB4 + (kc), &lsB[slot][lo + 6144]);  \
    } while (0)

    FSTAGEA(0, 0);
    FSTAGEB(0, 0);
    FSTAGEB(1, 32);
    for (int tk = 0; tk < 64; ++tk) {
        int ca = tk & 1;
        int cb = tk % 3;
        if (tk == 63) asm volatile("s_waitcnt vmcnt(0)" ::: "memory");
        else          asm volatile("s_waitcnt vmcnt(4)" ::: "memory");
        __builtin_amdgcn_s_barrier();
        __builtin_amdgcn_sched_barrier(0);
        if (tk + 1 < 64) FSTAGEA(ca ^ 1, (tk + 1) * 32);
        if (tk + 2 < 64) FSTAGEB((tk + 2) % 3, (tk + 2) * 32);
        f16x8 af[5], bf[7];
#pragma unroll
        for (int i = 0; i < 5; ++i) af[i] = *(const f16x8*)&lsA[ca][(wr * 80 + i * 16 + l15) * 32 + ((g * 8) ^ xsw)];
#pragma unroll
        for (int j = 0; j < 7; ++j) bf[j] = *(const f16x8*)&lsB[cb][(wc * 112 + j * 16 + l15) * 32 + ((g * 8) ^ xsw)];
        asm volatile("s_waitcnt lgkmcnt(0)" ::: "memory");
        __builtin_amdgcn_sched_barrier(0);
#pragma unroll
        for (int i = 0; i < 5; ++i)
#pragma unroll
            for (int j = 0; j < 7; ++j)
                acc[i][j] = __builtin_amdgcn_mfma_f32_16x16x32_f16(af[i], bf[j], acc[i][j], 0, 0, 0);
    }
#undef FSTAGEA
#undef FSTAGEB

#pragma unroll
    for (int i = 0; i < 5; ++i) {
#pragma unroll
        for (int pair = 0; pair < 2; ++pair) {
            float m = -3.0e38f;
#pragma unroll
            for (int j = 0; j < 7; ++j) {
                int col = wc * 112 + j * 16 + l15;
                if (col < N_) m = fmaxf(m, acc[i][j][2 * pair]);
            }
#pragma unroll
            for (int off = 1; off < 16; off <<= 1) m = fmaxf(m, __shfl_xor(m, off));
            float ls = 0.f, dt = 0.f;
#pragma unroll
            for (int j = 0; j < 7; ++j) {
                int col = wc * 112 + j * 16 + l15;
                if (col < N_) {
                    float p = __expf(acc[i][j][2 * pair] - m);
                    ls += p;
                    dt += p * acc[i][j][2 * pair + 1];
                }
            }
#pragma unroll
            for (int off = 1; off < 16; off <<= 1) { ls += __shfl_xor(ls, off); dt += __shfl_xor(dt, off); }
            if (l15 == 0) {
                int pr = wr * 40 + i * 8 + g * 2 + pair;
                lsE[wc][pr][0] = m; lsE[wc][pr][1] = ls; lsE[wc][pr][2] = dt;
            }
        }
    }
    __syncthreads();
    if (t < 80) {
        float m0 = lsE[0][t][0], l0 = lsE[0][t][1], dv0 = lsE[0][t][2];
        float m1 = lsE[1][t][0], l1 = lsE[1][t][1], dv1 = lsE[1][t][2];
        float M = fmaxf(m0, m1);
        float e0 = __expf(m0 - M), e1 = __expf(m1 - M);
        float L = l0 * e0 + l1 * e1, D = dv0 * e0 + dv1 * e1;
        int s = st * 80 + t;
        if (s < S_) {
            int bg = b0 + bb;
            out[(size_t)bg * S_ + s] = base2[(size_t)bg * S_ + s] + D / L;
        }
    }
}

// ===========================================================================
extern "C" void kernel_launch(void* const* d_in, const int* in_sizes, int n_in,
                              void* d_out, int out_size, void* d_ws, size_t ws_size,
                              hipStream_t stream) {
    const float* feat = (const float*)d_in[0];
    const float* att  = (const float*)d_in[1];
    const float* Wq   = (const float*)d_in[2];
    const float* bq   = (const float*)d_in[3];
    const float* Wk   = (const float*)d_in[4];
    /* bk = d_in[5] — per-s constant over n in scores: softmax-invariant, dropped */
    const float* Wv   = (const float*)d_in[6];
    const float* bv   = (const float*)d_in[7];
    const float* Wo   = (const float*)d_in[8];
    const float* bo   = (const float*)d_in[9];
    const float* V    = (const float*)d_in[10];
    float* out = (float*)d_out;

    auto AL = [](size_t x) { return (x + 255) & ~(size_t)255; };
    const size_t szAstk = (size_t)768 * C_ * 2;       // pair-interleaved [2s | 2s+1]
    const size_t szQh   = (size_t)SP * M_ * 2;
    const size_t szVh   = (size_t)SP * C_ * 2;
    const size_t szUh   = (size_t)SP * M_ * 2;
    const size_t szWT   = (size_t)C_ * M_ * 2;
    const size_t szAtth = (size_t)SP * LP * 2;
    const size_t szWqh  = (size_t)M_ * LP * 2;
    const size_t szPoolp = (size_t)4 * B_ * C_ * 4;
    const size_t szBase = (size_t)B_ * S_ * 4;
    const size_t szWobv = (size_t)C_ * 4;
    size_t fixed = AL(szAstk) + AL(szQh) + AL(szVh) + AL(szUh) + 3 * AL(szWT) +
                   AL(szAtth) + AL(szWqh) + AL(szPoolp) + AL(szBase) + AL(szWobv);

    int nsplit = 1;
    while (nsplit < 32) {
        size_t nB = B_ / nsplit;
        size_t need = fixed + AL(nB * NP * C_ * 2 + 131072);  // +128KB over-stage slack
        if (need <= ws_size) break;
        nsplit *= 2;
    }
    int nB = B_ / nsplit;

    char* p = (char*)d_ws;
    half_t* AstackP = (half_t*)p; p += AL(szAstk);
    half_t* qh     = (half_t*)p; p += AL(szQh);
    half_t* Vh     = (half_t*)p; p += AL(szVh);
    half_t* Uh     = (half_t*)p; p += AL(szUh);
    half_t* WkT    = (half_t*)p; p += AL(szWT);
    half_t* WoT    = (half_t*)p; p += AL(szWT);
    half_t* WvT    = (half_t*)p; p += AL(szWT);
    half_t* atth   = (half_t*)p; p += AL(szAtth);
    half_t* wqh    = (half_t*)p; p += AL(szWqh);
    float*  poolp  = (float*)p;  p += AL(szPoolp);
    float*  base2  = (float*)p;  p += AL(szBase);
    float*  Wobv   = (float*)p;  p += AL(szWobv);
    half_t* featT  = (half_t*)p;

    GDesc dq{atth, wqh, nullptr, qh, bq, LP, M_, 1, 0};
    GDesc dU{Vh, WoT, nullptr, Uh, nullptr, C_, M_, 1, 0};
    GDesc dk{qh, WkT, nullptr, AstackP, nullptr, M_, C_, 2, 0};
    GDesc dv{Uh, WvT, nullptr, AstackP, nullptr, M_, C_, 2, 1};

    if (nsplit == 1) {
        // D1: transf || convert+Wobv || weight transposes
        k_d1<<<dim3(16384 + 1720 + 1536), 256, 0, stream>>>(feat, att, Wq, V, Wo, bv, Wk, Wv,
                                                            featT, poolp, atth, wqh, Vh, Wobv,
                                                            WkT, WoT, WvT);
        // D2: prepA (q, U) || poolv
        k_d2<<<dim3(560), 256, 0, stream>>>(dq, dU, poolp, bo, Wobv, V, base2);
        // D3: prepB (Qk -> rows 2s, Wv2 -> rows 2s+1)
        k_prep2<<<dim3(16, 3, 2), 256, 0, stream>>>(dk, dv);
        // D4: fused scores/W2 + softmax + dot
        k_fused<<<dim3(B_, 4), 256, 0, stream>>>(AstackP, featT, base2, out, 0);
    } else {
        k_misc<<<dim3(1720 + 1536), 256, 0, stream>>>(att, Wq, V, Wo, bv, Wk, Wv,
                                                      atth, wqh, Vh, Wobv, WkT, WoT, WvT);
        k_prep2<<<dim3(8, 3, 2), 256, 0, stream>>>(dq, dU);
        k_prep2<<<dim3(16, 3, 2), 256, 0, stream>>>(dk, dv);
        for (int h = 0; h < nsplit; ++h) {
            const float* fh = feat + (size_t)h * nB * C_ * N_;
            k_transf_only<<<dim3(4, 32, nB), 256, 0, stream>>>(fh, featT, poolp);
            k_poolv_only<<<dim3(4, nB), 256, 0, stream>>>(poolp, bo, Wobv, V, base2 + (size_t)h * nB * S_);
            k_fused<<<dim3(nB, 4), 256, 0, stream>>>(AstackP, featT, base2, out, h * nB);
        }
    }
}

// Round 11
// 217.744 us; speedup vs baseline: 2.2600x; 1.0014x over previous
//
#include <hip/hip_runtime.h>
#include <hip/hip_bf16.h>
#include <cstdint>

typedef _Float16 half_t;
typedef _Float16 f16x8 __attribute__((ext_vector_type(8), aligned(16)));
typedef _Float16 f16x4 __attribute__((ext_vector_type(4), aligned(8)));
typedef _Float16 f16x2 __attribute__((ext_vector_type(2), aligned(4)));
typedef float f32x4 __attribute__((ext_vector_type(4)));

#define B_ 128
#define C_ 2048
#define N_ 196
#define S_ 312
#define L_ 300
#define LP 320   // padded L (10 x 32)
#define M_ 1024
#define NP 224   // padded N (14 x 16)
#define SP 384   // padded S for prep GEMMs (3 x 128)

// ---- async global->LDS, 16B per lane ----
__device__ __forceinline__ void gload16(const half_t* g, half_t* l) {
    __builtin_amdgcn_global_load_lds((const __attribute__((address_space(1))) void*)g,
                                     (__attribute__((address_space(3))) void*)l, 16, 0, 0);
}

struct GDesc {
    const half_t* A; const half_t* Bm;
    float* outF; half_t* outH; const float* bias;
    int kdim; int ldo; int rowmul; int rowoff;
};

// ===========================================================================
// Device role bodies
// ===========================================================================

// ---- convert/pad + Wobv: role index c in [0,1720) ----
__device__ __forceinline__ void dev_convert(int c, int t, const float* __restrict__ att,
                                            const float* __restrict__ Wq, const float* __restrict__ V,
                                            const float* __restrict__ Wo, const float* __restrict__ bv,
                                            half_t* __restrict__ atth, half_t* __restrict__ wqh,
                                            half_t* __restrict__ vh, float* __restrict__ Wobv) {
    if (c < 120) {            // att [312,300] -> [384,320]
        size_t e = ((size_t)c * 256 + t) * 4;
        int r = (int)(e / LP), cc = (int)(e % LP);
        f16x4 h;
#pragma unroll
        for (int j = 0; j < 4; ++j) h[j] = (half_t)((r < S_ && cc + j < L_) ? att[(size_t)r * L_ + cc + j] : 0.f);
        *(f16x4*)&atth[e] = h;
    } else if (c < 440) {     // Wq [1024,300] -> [1024,320]
        size_t e = ((size_t)(c - 120) * 256 + t) * 4;
        int r = (int)(e / LP), cc = (int)(e % LP);
        f16x4 h;
#pragma unroll
        for (int j = 0; j < 4; ++j) h[j] = (half_t)((cc + j < L_) ? Wq[(size_t)r * L_ + cc + j] : 0.f);
        *(f16x4*)&wqh[e] = h;
    } else if (c < 1208) {    // V [312,2048] -> [384,2048]
        size_t e = ((size_t)(c - 440) * 256 + t) * 4;
        int r = (int)(e / C_);
        f16x4 h;
        if (r < S_) {
            float4 v = *(const float4*)&V[e];
            h[0] = (half_t)v.x; h[1] = (half_t)v.y; h[2] = (half_t)v.z; h[3] = (half_t)v.w;
        } else {
            h[0] = h[1] = h[2] = h[3] = (half_t)0.f;
        }
        *(f16x4*)&vh[e] = h;
    } else {                  // Wobv[cc] = sum_m Wo[cc][m]*bv[m]
        int cc = (c - 1208) * 4 + (t >> 6);
        int lane = t & 63;
        const float* wr_ = Wo + (size_t)cc * M_;
        float acc = 0;
#pragma unroll
        for (int i = 0; i < 16; ++i) acc += wr_[lane + 64 * i] * bv[lane + 64 * i];
        for (int off = 32; off; off >>= 1) acc += __shfl_xor(acc, off);
        if (lane == 0) Wobv[cc] = acc;
    }
}

// ---- weight transposes: role index r3 in [0,1536) ----
__device__ __forceinline__ void dev_transp3(int r3, int t, const float* __restrict__ Wk,
                                            const float* __restrict__ Wo, const float* __restrict__ Wv,
                                            half_t* __restrict__ WkT, half_t* __restrict__ WoT,
                                            half_t* __restrict__ WvT, char* smc) {
    half_t (*lsT)[72] = (half_t(*)[72])smc;
    int z = r3 >> 9, r = r3 & 511;
    const float* in; half_t* out; int R, Cc, bx, by;
    if (z == 0)      { in = Wk; out = WkT; R = 1024; Cc = 2048; bx = r & 31; by = r >> 5; }
    else if (z == 1) { in = Wo; out = WoT; R = 2048; Cc = 1024; bx = r & 15; by = r >> 4; }
    else             { in = Wv; out = WvT; R = 1024; Cc = 2048; bx = r & 31; by = r >> 5; }
    int c0 = bx * 64, r0 = by * 64;
#pragma unroll
    for (int i = 0; i < 4; ++i) {
        int Q = t + 256 * i;
        int rq = Q >> 5, cq = Q & 31;
        int rr = 2 * rq, cc = 2 * cq;
        const float* p0 = in + (size_t)(r0 + rr) * Cc + c0 + cc;
        float2 va = *(const float2*)p0;
        float2 vb = *(const float2*)(p0 + Cc);
        f16x2 w0; w0[0] = (half_t)va.x; w0[1] = (half_t)vb.x;
        f16x2 w1; w1[0] = (half_t)va.y; w1[1] = (half_t)vb.y;
        *(f16x2*)&lsT[cc][rr]     = w0;   // lsT[c][r] = in[r][c]
        *(f16x2*)&lsT[cc + 1][rr] = w1;
    }
    __syncthreads();
    int cl = t >> 2, ch = t & 3;
    f16x8 v0 = *(const f16x8*)&lsT[cl][ch * 16];
    f16x8 v1 = *(const f16x8*)&lsT[cl][ch * 16 + 8];
    half_t* po = out + (size_t)(c0 + cl) * R + r0 + ch * 16;
    *(f16x8*)po = v0;
    *(f16x8*)(po + 8) = v1;
}

// ---- feat transpose+convert + pool partials (float4 + XOR-swizzled LDS) ----
// LDS: 64 rows x 144B; logical [n][c] f16; physical bytecol = logical ^ (((row>>2)&7)<<4).
// Writes: 4B f16x2, bank pattern exactly 2-way.  Reads: 16B, alignment preserved by XOR.
__device__ __forceinline__ void dev_transf(const float* __restrict__ feat, half_t* __restrict__ featT,
                                           float* __restrict__ poolp, int nT, int cT, int bb, int t, char* smc) {
    char* lsTb = smc;
    float* poolLs = (float*)(smc + 64 * 144);
    int n0 = nT * 64, c0 = cT * 64;
    const float* fb = feat + (size_t)bb * C_ * N_;
#pragma unroll
    for (int i = 0; i < 2; ++i) {
        int Q = t + 256 * i;
        int nq = Q & 15, cq = Q >> 4;          // cq 0..31 over both iters
        int cc = 2 * cq, nn = 4 * nq;
        int n = n0 + nn;
        float4 va = {0, 0, 0, 0}, vb = {0, 0, 0, 0};
        if (n < N_) {   // N_=196 = 49 float4s: n<196 => n..n+3 all valid; 16B-aligned (784=49*16)
            const float* p0 = fb + (size_t)(c0 + cc) * N_ + n;
            va = *(const float4*)p0;
            vb = *(const float4*)(p0 + N_);
        }
        int key = (nq & 7) << 4;               // (row>>2)&7 == nq&7 for rows nn..nn+3
        char* base = lsTb + (size_t)nn * 144 + ((4 * cq) ^ key);
        f16x2 w0; w0[0] = (half_t)va.x; w0[1] = (half_t)vb.x;
        f16x2 w1; w1[0] = (half_t)va.y; w1[1] = (half_t)vb.y;
        f16x2 w2; w2[0] = (half_t)va.z; w2[1] = (half_t)vb.z;
        f16x2 w3; w3[0] = (half_t)va.w; w3[1] = (half_t)vb.w;
        *(f16x2*)(base)       = w0;            // row nn   (same key for all 4 rows)
        *(f16x2*)(base + 144) = w1;            // row nn+1
        *(f16x2*)(base + 288) = w2;            // row nn+2
        *(f16x2*)(base + 432) = w3;            // row nn+3
        float sA = va.x + va.y + va.z + va.w;
        float sB = vb.x + vb.y + vb.z + vb.w;
#pragma unroll
        for (int off = 1; off < 16; off <<= 1) { sA += __shfl_xor(sA, off); sB += __shfl_xor(sB, off); }
        if (nq == 0) { poolLs[cc] = sA; poolLs[cc + 1] = sB; }
    }
    __syncthreads();
    int nl = t >> 2, ch = t & 3;
    int n = n0 + nl;
    if (n < NP) {   // rows [224,256) of nT=3 must NOT spill into the next batch's tile
        int key = ((nl >> 2) & 7) << 4;
        const char* rb = lsTb + (size_t)nl * 144;
        f16x8 v0 = *(const f16x8*)(rb + ((32 * ch) ^ key));
        f16x8 v1 = *(const f16x8*)(rb + ((32 * ch + 16) ^ key));
        half_t* po = featT + ((size_t)bb * NP + n) * C_ + c0 + ch * 16;
        *(f16x8*)po = v0;
        *(f16x8*)(po + 8) = v1;
    }
    if (t < 64) poolp[((size_t)nT * B_ + bb) * C_ + c0 + t] = poolLs[t];
}

// ---- prep GEMM (counted-vmcnt 3-slot ring + XOR-swizzled LDS), R5-proven body ----
__device__ __forceinline__ void dev_prep(GDesc d, int bx, int by, int t, char* smc) {
    half_t* lsA = (half_t*)smc;            // 3 slots x 4096 halves
    half_t* lsB = lsA + 3 * 4096;
    int wid = t >> 6, lane = t & 63;
    const int rA0 = by * 128, rB0 = bx * 128;
    int wr = wid >> 1, wc = wid & 1;
    int g = lane >> 4, l15 = lane & 15;
    const int r_ = t >> 2;
    const int gsrc = ((t & 3) ^ ((t >> 3) & 3)) * 8;
    const int kdim = d.kdim;
    const half_t* pA  = d.A + (size_t)(rA0 + r_) * kdim + gsrc;
    const half_t* pA2 = pA + (size_t)64 * kdim;
    const half_t* pB  = d.Bm + (size_t)(rB0 + r_) * kdim + gsrc;
    const half_t* pB2 = pB + (size_t)64 * kdim;
    const int lo = t * 8;
    const int xsw = ((l15 >> 1) & 3) * 8;
    f32x4 acc[4][4] = {};
    int nk = kdim >> 5;

#define PSTAGE(slot, kc)                                    \
    do {                                                    \
        gload16(pA + (kc), &lsA[(slot) * 4096 + lo]);       \
        gload16(pA2 + (kc), &lsA[(slot) * 4096 + lo + 2048]); \
        gload16(pB + (kc), &lsB[(slot) * 4096 + lo]);       \
        gload16(pB2 + (kc), &lsB[(slot) * 4096 + lo + 2048]); \
    } while (0)

    PSTAGE(0, 0);
    PSTAGE(1, 32);
    int cur = 0, nxt = 2;
    for (int tk = 0; tk < nk; ++tk) {
        if (tk == nk - 1) asm volatile("s_waitcnt vmcnt(0)" ::: "memory");
        else              asm volatile("s_waitcnt vmcnt(4)" ::: "memory");
        __builtin_amdgcn_s_barrier();
        __builtin_amdgcn_sched_barrier(0);
        f16x8 af[4], bf[4];
#pragma unroll
        for (int i = 0; i < 4; ++i) af[i] = *(const f16x8*)&lsA[cur * 4096 + (wr * 64 + i * 16 + l15) * 32 + ((g * 8) ^ xsw)];
#pragma unroll
        for (int j = 0; j < 4; ++j) bf[j] = *(const f16x8*)&lsB[cur * 4096 + (wc * 64 + j * 16 + l15) * 32 + ((g * 8) ^ xsw)];
        if (tk + 2 < nk) PSTAGE(nxt, (tk + 2) * 32);
#pragma unroll
        for (int i = 0; i < 4; ++i)
#pragma unroll
            for (int j = 0; j < 4; ++j)
                acc[i][j] = __builtin_amdgcn_mfma_f32_16x16x32_f16(af[i], bf[j], acc[i][j], 0, 0, 0);
        cur = (cur == 2) ? 0 : cur + 1;
        nxt = (nxt == 2) ? 0 : nxt + 1;
    }
#undef PSTAGE

#pragma unroll
    for (int i = 0; i < 4; ++i) {
        int r0 = rA0 + wr * 64 + i * 16 + g * 4;
#pragma unroll
        for (int j = 0; j < 4; ++j) {
            int c0 = rB0 + wc * 64 + j * 16 + l15;
            float bval = d.bias ? d.bias[c0] : 0.f;
#pragma unroll
            for (int qq = 0; qq < 4; ++qq) {
                int rr = (r0 + qq) * d.rowmul + d.rowoff;
                float val = acc[i][j][qq];
                if (d.outF) d.outF[(size_t)rr * d.ldo + c0] = val;
                if (d.outH) d.outH[(size_t)rr * d.ldo + c0] = (half_t)(val + bval);
            }
        }
    }
}

// ---- pool+V dot: base2[b][s] = sum_c (pool[b][c]+bo[c]+Wobv[c]) * V[s][c] ----
__device__ __forceinline__ void dev_poolv(const float* __restrict__ poolp, const float* __restrict__ bo,
                                          const float* __restrict__ Wobv, const float* __restrict__ V,
                                          float* __restrict__ base2, int sc, int b, int t, char* smc) {
    float* w = (float*)smc;
    for (int i = t; i < C_; i += 256) {
        float s = poolp[(size_t)b * C_ + i] + poolp[((size_t)B_ + b) * C_ + i] +
                  poolp[((size_t)2 * B_ + b) * C_ + i] + poolp[((size_t)3 * B_ + b) * C_ + i];
        w[i] = s * (1.0f / 196.0f) + bo[i] + Wobv[i];
    }
    __syncthreads();
    int wid = t >> 6, lane = t & 63;
    for (int s = sc * 78 + wid; s < sc * 78 + 78; s += 4) {
        const float* vr = V + (size_t)s * C_;
        float acc = 0;
#pragma unroll
        for (int i = 0; i < 32; ++i) acc += w[lane + 64 * i] * vr[lane + 64 * i];
        for (int off = 32; off; off >>= 1) acc += __shfl_xor(acc, off);
        if (lane == 0) base2[(size_t)b * S_ + s] = acc;
    }
}

// ===========================================================================
// Umbrella dispatches
// ===========================================================================

// D1: transf (16384) | convert+Wobv (1720) | transp3 (1536).  grid 19640, block 256
__global__ __launch_bounds__(256) void k_d1(const float* __restrict__ feat, const float* __restrict__ att,
                                            const float* __restrict__ Wq, const float* __restrict__ V,
                                            const float* __restrict__ Wo, const float* __restrict__ bv,
                                            const float* __restrict__ Wk, const float* __restrict__ Wv,
                                            half_t* __restrict__ featT, float* __restrict__ poolp,
                                            half_t* __restrict__ atth, half_t* __restrict__ wqh,
                                            half_t* __restrict__ vh, float* __restrict__ Wobv,
                                            half_t* __restrict__ WkT, half_t* __restrict__ WoT,
                                            half_t* __restrict__ WvT) {
    __shared__ __attribute__((aligned(16))) char sm[9472];
    int x = blockIdx.x, t = threadIdx.x;
    if (x < 16384) {
        dev_transf(feat, featT, poolp, x & 3, (x >> 2) & 31, x >> 7, t, sm);
    } else if (x < 16384 + 1720) {
        dev_convert(x - 16384, t, att, Wq, V, Wo, bv, atth, wqh, vh, Wobv);
    } else {
        dev_transp3(x - 16384 - 1720, t, Wk, Wo, Wv, WkT, WoT, WvT, sm);
    }
}

// D2: prepA (48: q & U GEMMs) | poolv (512).  grid 560, block 256
__global__ __launch_bounds__(256) void k_d2(GDesc dq, GDesc dU, const float* __restrict__ poolp,
                                            const float* __restrict__ bo, const float* __restrict__ Wobv,
                                            const float* __restrict__ V, float* __restrict__ base2) {
    __shared__ __attribute__((aligned(16))) char sm[49152];
    int x = blockIdx.x, t = threadIdx.x;
    if (x < 48) {
        dev_prep((x / 24) ? dU : dq, x & 7, (x >> 3) % 3, t, sm);
    } else {
        int r = x - 48;
        dev_poolv(poolp, bo, Wobv, V, base2, r & 3, r >> 2, t, sm);
    }
}

// D3 (and legacy prep): dual-descriptor prep GEMM.  grid (gx,3,2)
__global__ __launch_bounds__(256) void k_prep2(GDesc d0, GDesc d1) {
    __shared__ __attribute__((aligned(16))) char sm[49152];
    dev_prep(blockIdx.z ? d1 : d0, blockIdx.x, blockIdx.y, threadIdx.x, sm);
}

// Legacy helpers (nsplit > 1 fallback)
__global__ __launch_bounds__(256) void k_misc(const float* att, const float* Wq, const float* V,
                                              const float* Wo, const float* bv, const float* Wk,
                                              const float* Wv, half_t* atth, half_t* wqh, half_t* vh,
                                              float* Wobv, half_t* WkT, half_t* WoT, half_t* WvT) {
    __shared__ __attribute__((aligned(16))) char sm[9472];
    int x = blockIdx.x, t = threadIdx.x;
    if (x < 1720) dev_convert(x, t, att, Wq, V, Wo, bv, atth, wqh, vh, Wobv);
    else          dev_transp3(x - 1720, t, Wk, Wo, Wv, WkT, WoT, WvT, sm);
}
__global__ __launch_bounds__(256) void k_transf_only(const float* feat, half_t* featT, float* poolp) {
    __shared__ __attribute__((aligned(16))) char sm[9472];
    dev_transf(feat, featT, poolp, blockIdx.x, blockIdx.y, blockIdx.z, threadIdx.x, sm);
}
__global__ __launch_bounds__(256) void k_poolv_only(const float* poolp, const float* bo, const float* Wobv,
                                                    const float* V, float* base2) {
    __shared__ __attribute__((aligned(16))) char sm[8192];
    dev_poolv(poolp, bo, Wobv, V, base2, blockIdx.x, blockIdx.y, threadIdx.x, sm);
}

// ===========================================================================
// D4: fused main kernel — unchanged from R9 (160-row tile, asymmetric counted ring)
// ===========================================================================
__global__ __launch_bounds__(256) void k_fused(const half_t* __restrict__ AstackP, const half_t* __restrict__ featT,
                                               const float* __restrict__ base2, float* __restrict__ out, int b0) {
    __shared__ __attribute__((aligned(16))) half_t lsA[2][192 * 32];
    __shared__ __attribute__((aligned(16))) half_t lsB[3][256 * 32];
    __shared__ float lsE[2][80][4];
    int t = threadIdx.x;
    int bb = blockIdx.x, st = blockIdx.y;
    int wid = t >> 6, lane = t & 63;
    int wr = wid >> 1, wc = wid & 1;
    int g = lane >> 4, l15 = lane & 15;
    const int gsrc = ((t & 3) ^ ((t >> 3) & 3)) * 8;
    const half_t* pA  = AstackP + ((size_t)st * 160 + (t >> 2)) * C_ + gsrc;
    const half_t* pA2 = pA + (size_t)64 * C_;
    const half_t* pA3 = pA + (size_t)128 * C_;
    const half_t* pB  = featT + ((size_t)bb * NP + (t >> 2)) * C_ + gsrc;
    const half_t* pB2 = pB + (size_t)64 * C_;
    const half_t* pB3 = pB + (size_t)128 * C_;
    const half_t* pB4 = pB + (size_t)192 * C_;
    const int lo = t * 8;
    const int xsw = ((l15 >> 1) & 3) * 8;
    f32x4 acc[5][7] = {};

#define FSTAGEA(slot, kc)                            \
    do {                                             \
        gload16(pA + (kc), &lsA[slot][lo]);          \
        gload16(pA2 + (kc), &lsA[slot][lo + 2048]);  \
        gload16(pA3 + (kc), &lsA[slot][lo + 4096]);  \
    } while (0)
#define FSTAGEB(slot, kc)                            \
    do {                                             \
        gload16(pB + (kc), &lsB[slot][lo]);          \
        gload16(pB2 + (kc), &lsB[slot][lo + 2048]);  \
        gload16(pB3 + (kc), &lsB[slot][lo + 4096]);  \
        gload16(pB4 + (kc), &lsB[slot][lo + 6144]);  \
    } while (0)

    FSTAGEA(0, 0);
    FSTAGEB(0, 0);
    FSTAGEB(1, 32);
    for (int tk = 0; tk < 64; ++tk) {
        int ca = tk & 1;
        int cb = tk % 3;
        if (tk == 63) asm volatile("s_waitcnt vmcnt(0)" ::: "memory");
        else          asm volatile("s_waitcnt vmcnt(4)" ::: "memory");
        __builtin_amdgcn_s_barrier();
        __builtin_amdgcn_sched_barrier(0);
        if (tk + 1 < 64) FSTAGEA(ca ^ 1, (tk + 1) * 32);
        if (tk + 2 < 64) FSTAGEB((tk + 2) % 3, (tk + 2) * 32);
        f16x8 af[5], bf[7];
#pragma unroll
        for (int i = 0; i < 5; ++i) af[i] = *(const f16x8*)&lsA[ca][(wr * 80 + i * 16 + l15) * 32 + ((g * 8) ^ xsw)];
#pragma unroll
        for (int j = 0; j < 7; ++j) bf[j] = *(const f16x8*)&lsB[cb][(wc * 112 + j * 16 + l15) * 32 + ((g * 8) ^ xsw)];
        asm volatile("s_waitcnt lgkmcnt(0)" ::: "memory");
        __builtin_amdgcn_sched_barrier(0);
#pragma unroll
        for (int i = 0; i < 5; ++i)
#pragma unroll
            for (int j = 0; j < 7; ++j)
                acc[i][j] = __builtin_amdgcn_mfma_f32_16x16x32_f16(af[i], bf[j], acc[i][j], 0, 0, 0);
    }
#undef FSTAGEA
#undef FSTAGEB

#pragma unroll
    for (int i = 0; i < 5; ++i) {
#pragma unroll
        for (int pair = 0; pair < 2; ++pair) {
            float m = -3.0e38f;
#pragma unroll
            for (int j = 0; j < 7; ++j) {
                int col = wc * 112 + j * 16 + l15;
                if (col < N_) m = fmaxf(m, acc[i][j][2 * pair]);
            }
#pragma unroll
            for (int off = 1; off < 16; off <<= 1) m = fmaxf(m, __shfl_xor(m, off));
            float ls = 0.f, dt = 0.f;
#pragma unroll
            for (int j = 0; j < 7; ++j) {
                int col = wc * 112 + j * 16 + l15;
                if (col < N_) {
                    float p = __expf(acc[i][j][2 * pair] - m);
                    ls += p;
                    dt += p * acc[i][j][2 * pair + 1];
                }
            }
#pragma unroll
            for (int off = 1; off < 16; off <<= 1) { ls += __shfl_xor(ls, off); dt += __shfl_xor(dt, off); }
            if (l15 == 0) {
                int pr = wr * 40 + i * 8 + g * 2 + pair;
                lsE[wc][pr][0] = m; lsE[wc][pr][1] = ls; lsE[wc][pr][2] = dt;
            }
        }
    }
    __syncthreads();
    if (t < 80) {
        float m0 = lsE[0][t][0], l0 = lsE[0][t][1], dv0 = lsE[0][t][2];
        float m1 = lsE[1][t][0], l1 = lsE[1][t][1], dv1 = lsE[1][t][2];
        float M = fmaxf(m0, m1);
        float e0 = __expf(m0 - M), e1 = __expf(m1 - M);
        float L = l0 * e0 + l1 * e1, D = dv0 * e0 + dv1 * e1;
        int s = st * 80 + t;
        if (s < S_) {
            int bg = b0 + bb;
            out[(size_t)bg * S_ + s] = base2[(size_t)bg * S_ + s] + D / L;
        }
    }
}

// ===========================================================================
extern "C" void kernel_launch(void* const* d_in, const int* in_sizes, int n_in,
                              void* d_out, int out_size, void* d_ws, size_t ws_size,
                              hipStream_t stream) {
    const float* feat = (const float*)d_in[0];
    const float* att  = (const float*)d_in[1];
    const float* Wq   = (const float*)d_in[2];
    const float* bq   = (const float*)d_in[3];
    const float* Wk   = (const float*)d_in[4];
    /* bk = d_in[5] — per-s constant over n in scores: softmax-invariant, dropped */
    const float* Wv   = (const float*)d_in[6];
    const float* bv   = (const float*)d_in[7];
    const float* Wo   = (const float*)d_in[8];
    const float* bo   = (const float*)d_in[9];
    const float* V    = (const float*)d_in[10];
    float* out = (float*)d_out;

    auto AL = [](size_t x) { return (x + 255) & ~(size_t)255; };
    const size_t szAstk = (size_t)768 * C_ * 2;       // pair-interleaved [2s | 2s+1]
    const size_t szQh   = (size_t)SP * M_ * 2;
    const size_t szVh   = (size_t)SP * C_ * 2;
    const size_t szUh   = (size_t)SP * M_ * 2;
    const size_t szWT   = (size_t)C_ * M_ * 2;
    const size_t szAtth = (size_t)SP * LP * 2;
    const size_t szWqh  = (size_t)M_ * LP * 2;
    const size_t szPoolp = (size_t)4 * B_ * C_ * 4;
    const size_t szBase = (size_t)B_ * S_ * 4;
    const size_t szWobv = (size_t)C_ * 4;
    size_t fixed = AL(szAstk) + AL(szQh) + AL(szVh) + AL(szUh) + 3 * AL(szWT) +
                   AL(szAtth) + AL(szWqh) + AL(szPoolp) + AL(szBase) + AL(szWobv);

    int nsplit = 1;
    while (nsplit < 32) {
        size_t nB = B_ / nsplit;
        size_t need = fixed + AL(nB * NP * C_ * 2 + 131072);  // +128KB over-stage slack
        if (need <= ws_size) break;
        nsplit *= 2;
    }
    int nB = B_ / nsplit;

    char* p = (char*)d_ws;
    half_t* AstackP = (half_t*)p; p += AL(szAstk);
    half_t* qh     = (half_t*)p; p += AL(szQh);
    half_t* Vh     = (half_t*)p; p += AL(szVh);
    half_t* Uh     = (half_t*)p; p += AL(szUh);
    half_t* WkT    = (half_t*)p; p += AL(szWT);
    half_t* WoT    = (half_t*)p; p += AL(szWT);
    half_t* WvT    = (half_t*)p; p += AL(szWT);
    half_t* atth   = (half_t*)p; p += AL(szAtth);
    half_t* wqh    = (half_t*)p; p += AL(szWqh);
    float*  poolp  = (float*)p;  p += AL(szPoolp);
    float*  base2  = (float*)p;  p += AL(szBase);
    float*  Wobv   = (float*)p;  p += AL(szWobv);
    half_t* featT  = (half_t*)p;

    GDesc dq{atth, wqh, nullptr, qh, bq, LP, M_, 1, 0};
    GDesc dU{Vh, WoT, nullptr, Uh, nullptr, C_, M_, 1, 0};
    GDesc dk{qh, WkT, nullptr, AstackP, nullptr, M_, C_, 2, 0};
    GDesc dv{Uh, WvT, nullptr, AstackP, nullptr, M_, C_, 2, 1};

    if (nsplit == 1) {
        // D1: transf || convert+Wobv || weight transposes
        k_d1<<<dim3(16384 + 1720 + 1536), 256, 0, stream>>>(feat, att, Wq, V, Wo, bv, Wk, Wv,
                                                            featT, poolp, atth, wqh, Vh, Wobv,
                                                            WkT, WoT, WvT);
        // D2: prepA (q, U) || poolv
        k_d2<<<dim3(560), 256, 0, stream>>>(dq, dU, poolp, bo, Wobv, V, base2);
        // D3: prepB (Qk -> rows 2s, Wv2 -> rows 2s+1)
        k_prep2<<<dim3(16, 3, 2), 256, 0, stream>>>(dk, dv);
        // D4: fused scores/W2 + softmax + dot
        k_fused<<<dim3(B_, 4), 256, 0, stream>>>(AstackP, featT, base2, out, 0);
    } else {
        k_misc<<<dim3(1720 + 1536), 256, 0, stream>>>(att, Wq, V, Wo, bv, Wk, Wv,
                                                      atth, wqh, Vh, Wobv, WkT, WoT, WvT);
        k_prep2<<<dim3(8, 3, 2), 256, 0, stream>>>(dq, dU);
        k_prep2<<<dim3(16, 3, 2), 256, 0, stream>>>(dk, dv);
        for (int h = 0; h < nsplit; ++h) {
            const float* fh = feat + (size_t)h * nB * C_ * N_;
            k_transf_only<<<dim3(4, 32, nB), 256, 0, stream>>>(fh, featT, poolp);
            k_poolv_only<<<dim3(4, nB), 256, 0, stream>>>(poolp, bo, Wobv, V, base2 + (size_t)h * nB * S_);
            k_fused<<<dim3(nB, 4), 256, 0, stream>>>(AstackP, featT, base2, out, h * nB);
        }
    }
}